// Round 1
// baseline (954.109 us; speedup 1.0000x reference)
//
#include <hip/hip_runtime.h>

static constexpr int B_ = 64, T_ = 2048, I_ = 150, C_ = 3;

// workspace layout (float offsets)
static constexpr long XG1_OFF   = 0;                       // B*T*128 = 16777216
static constexpr long H1_OFF    = 16777216;                // B*T*32  = 4194304
static constexpr long H2_OFF    = H1_OFF + 4194304;        // B*T*2   = 262144
static constexpr long WPAD_OFF  = H2_OFF + 262144;         // 128*152 = 19456
static constexpr long BCOMB_OFF = WPAD_OFF + 19456;        // 128

#define LOG2E 1.4426950408889634f

__device__ __forceinline__ float fast_exp2(float x){ return __builtin_amdgcn_exp2f(x); }
__device__ __forceinline__ float fast_rcp(float x){ return __builtin_amdgcn_rcpf(x); }
__device__ __forceinline__ float sigm(float x){ return fast_rcp(1.f + fast_exp2(-LOG2E*x)); }
__device__ __forceinline__ float tanh_f(float x){
  return fmaf(2.f, fast_rcp(1.f + fast_exp2(-2.f*LOG2E*x)), -1.f);
}
__device__ __forceinline__ float bcastlane(float v, int l){
  return __uint_as_float(__builtin_amdgcn_readlane(__float_as_uint(v), l));
}

// ---------------------------------------------------------------- prep
// Build padded/concatenated W_ih1 [128][152] (fwd gates 0..63, bwd 64..127)
// and combined bias[128].
__global__ void prep_kernel(const float* __restrict__ wf, const float* __restrict__ wb,
                            const float* __restrict__ bf, const float* __restrict__ bb,
                            float* __restrict__ wpad, float* __restrict__ bcomb){
  int idx = blockIdx.x * 256 + threadIdx.x;   // exactly 128*152 threads
  int g = idx / 152, k = idx - g * 152;
  float v = 0.f;
  if (k < 150) v = (g < 64) ? wf[g*150 + k] : wb[(g-64)*150 + k];
  wpad[idx] = v;
  if (idx < 128) bcomb[idx] = (idx < 64) ? bf[idx] : bb[idx - 64];
}

// ---------------------------------------------------------------- xg1
// xg1[row][g] = bias[g] + sum_k x[row][k] * Wih[g][k];  row = b*T + t, g in [0,128)
__global__ void __launch_bounds__(256) xg1_kernel(
    const float* __restrict__ x, const float* __restrict__ wpad,
    const float* __restrict__ bcomb, float* __restrict__ xg){
  __shared__ float xs[64 * 152];
  const int tid = threadIdx.x;
  const long rowbase = (long)blockIdx.x * 64;
  for (int idx = tid; idx < 64 * 150; idx += 256){
    int r = idx / 150;
    int k = idx - r * 150;
    xs[r*152 + k] = x[(rowbase + r)*150 + k];
  }
  __syncthreads();
  const int gg = tid & 15;    // gate group: gates gg*8 .. gg*8+7
  const int rr = tid >> 4;    // row group:  rows  rr*4 .. rr*4+3
  const float* wp  = wpad + gg*8*152;
  const float* xsp = xs + rr*4*152;
  float bias[8];
  #pragma unroll
  for (int i = 0; i < 8; i++) bias[i] = bcomb[gg*8 + i];
  float acc[4][8];
  #pragma unroll
  for (int r = 0; r < 4; r++)
    #pragma unroll
    for (int i = 0; i < 8; i++) acc[r][i] = bias[i];

  for (int k = 0; k < 148; k += 4){
    float4 xv[4], wv[8];
    #pragma unroll
    for (int r = 0; r < 4; r++) xv[r] = *(const float4*)(xsp + r*152 + k);
    #pragma unroll
    for (int i = 0; i < 8; i++) wv[i] = *(const float4*)(wp + i*152 + k);
    #pragma unroll
    for (int r = 0; r < 4; r++)
      #pragma unroll
      for (int i = 0; i < 8; i++){
        acc[r][i] = fmaf(xv[r].x, wv[i].x, acc[r][i]);
        acc[r][i] = fmaf(xv[r].y, wv[i].y, acc[r][i]);
        acc[r][i] = fmaf(xv[r].z, wv[i].z, acc[r][i]);
        acc[r][i] = fmaf(xv[r].w, wv[i].w, acc[r][i]);
      }
  }
  { // tail k = 148,149
    const int k = 148;
    float2 xv[4], wv[8];
    #pragma unroll
    for (int r = 0; r < 4; r++) xv[r] = *(const float2*)(xsp + r*152 + k);
    #pragma unroll
    for (int i = 0; i < 8; i++) wv[i] = *(const float2*)(wp + i*152 + k);
    #pragma unroll
    for (int r = 0; r < 4; r++)
      #pragma unroll
      for (int i = 0; i < 8; i++){
        acc[r][i] = fmaf(xv[r].x, wv[i].x, acc[r][i]);
        acc[r][i] = fmaf(xv[r].y, wv[i].y, acc[r][i]);
      }
  }
  #pragma unroll
  for (int r = 0; r < 4; r++){
    long row = rowbase + rr*4 + r;
    float4 o0 = make_float4(acc[r][0], acc[r][1], acc[r][2], acc[r][3]);
    float4 o1 = make_float4(acc[r][4], acc[r][5], acc[r][6], acc[r][7]);
    float4* dst = (float4*)(xg + row*128 + gg*8);
    dst[0] = o0; dst[1] = o1;
  }
}

// ---------------------------------------------------------------- lstm1
// One wave per (batch, dir). lane = gate (64 gates = i,f,g,o x 16 units).
__global__ void __launch_bounds__(64) lstm1_kernel(
    const float* __restrict__ xg, const float* __restrict__ whf,
    const float* __restrict__ whb, float* __restrict__ h1){
  const int b = blockIdx.x >> 1, dir = blockIdx.x & 1, lane = threadIdx.x;
  const float* wh = dir ? whb : whf;
  float wrow[16];
  #pragma unroll
  for (int j = 0; j < 16; j++) wrow[j] = wh[lane*16 + j];
  const bool is_g = ((lane >> 4) == 2);       // gates 32..47 -> tanh
  const float A  = is_g ? 2.f : 1.f;
  const float ES = is_g ? (-2.f*LOG2E) : (-LOG2E);
  const float Bc = is_g ? -1.f : 0.f;
  const int li = lane & 15;

  const float* xcol = xg + ((long)b * T_) * 128 + dir*64 + lane;
  const int stride = dir ? -128 : 128;
  int coff = dir ? 2047*128 : 0;
  float* hptr = h1 + ((long)b*T_ + (dir ? 2047 : 0))*32 + dir*16 + li;
  const int hstride = dir ? -32 : 32;

  float h = 0.f, c = 0.f;
  float xb0[8], xb1[8];
  #pragma unroll
  for (int u = 0; u < 8; u++) xb0[u] = xcol[coff + u*stride];

  auto step = [&](float xgv){
    float a0 = xgv, a1 = 0.f, a2 = 0.f, a3 = 0.f;
    #pragma unroll
    for (int j = 0; j < 4; j++){
      a0 = fmaf(wrow[j],      bcastlane(h, j),      a0);
      a1 = fmaf(wrow[j + 4],  bcastlane(h, j + 4),  a1);
      a2 = fmaf(wrow[j + 8],  bcastlane(h, j + 8),  a2);
      a3 = fmaf(wrow[j + 12], bcastlane(h, j + 12), a3);
    }
    float s = (a0 + a1) + (a2 + a3);
    float act = fmaf(A, fast_rcp(1.f + fast_exp2(ES * s)), Bc);
    float gi = __shfl(act, li);
    float gf = __shfl(act, li + 16);
    float gG = __shfl(act, li + 32);
    float go = __shfl(act, li + 48);
    c = fmaf(gf, c, gi * gG);
    h = go * tanh_f(c);
    *hptr = h;                 // 4 replica lanes store identical value
    hptr += hstride;
  };

  for (int cc = 0; cc < 128; ++cc){
    #pragma unroll
    for (int u = 0; u < 8; u++) xb1[u] = xcol[coff + (8 + u)*stride];
    #pragma unroll
    for (int u = 0; u < 8; u++) step(xb0[u]);
    coff += 8*stride;
    if (cc < 127){
      #pragma unroll
      for (int u = 0; u < 8; u++) xb0[u] = xcol[coff + (8 + u)*stride];
    }
    #pragma unroll
    for (int u = 0; u < 8; u++) step(xb1[u]);
    coff += 8*stride;
  }
}

// ---------------------------------------------------------------- lstm2
// One wave per (batch, dir). Phase A: 4-gate input projection -> LDS.
// Phase B: serial H=1 scan (uniform on all lanes).
__global__ void __launch_bounds__(64) lstm2_kernel(
    const float* __restrict__ h1,
    const float* __restrict__ wi_f, const float* __restrict__ wi_b,
    const float* __restrict__ b_f,  const float* __restrict__ b_b,
    const float* __restrict__ u_f,  const float* __restrict__ u_b,
    float* __restrict__ h2){
  __shared__ float xg2[T_ * 4];
  const int b = blockIdx.x >> 1, dir = blockIdx.x & 1, lane = threadIdx.x;
  const float* wi = dir ? wi_b : wi_f;
  const float* bb = dir ? b_b  : b_f;
  const float* uu = dir ? u_b  : u_f;
  const int g = lane & 3, tslot = lane >> 2;
  float4 wv[8];
  #pragma unroll
  for (int q = 0; q < 8; q++) wv[q] = *(const float4*)(wi + g*32 + q*4);
  const float bg = bb[g];
  const float* h1b = h1 + (long)b * T_ * 32;
  for (int i = 0; i < 128; i++){
    int t = tslot + 16*i;
    const float4* hr = (const float4*)(h1b + (long)t * 32);
    float a = bg;
    #pragma unroll
    for (int q = 0; q < 8; q++){
      float4 hv = hr[q];
      a = fmaf(hv.x, wv[q].x, a); a = fmaf(hv.y, wv[q].y, a);
      a = fmaf(hv.z, wv[q].z, a); a = fmaf(hv.w, wv[q].w, a);
    }
    xg2[t*4 + g] = a;
  }
  __syncthreads();
  const float u0 = uu[0], u1 = uu[1], u2 = uu[2], u3 = uu[3];
  float h = 0.f, c = 0.f;
  float* outp = h2 + (long)b * T_ * 2 + dir;
  for (int n = 0; n < T_; n++){
    int t = dir ? (T_ - 1 - n) : n;
    float4 xv = *(const float4*)&xg2[t*4];
    float gi = sigm(fmaf(u0, h, xv.x));
    float gf = sigm(fmaf(u1, h, xv.y));
    float gG = tanh_f(fmaf(u2, h, xv.z));
    float go = sigm(fmaf(u3, h, xv.w));
    c = fmaf(gf, c, gi * gG);
    h = go * tanh_f(c);
    outp[(long)t * 2] = h;    // all lanes, same addr, same value
  }
}

// ---------------------------------------------------------------- head
// One wave per (batch, class): logits + softmax over T.
__global__ void __launch_bounds__(64) head_kernel(
    const float* __restrict__ h2, const float* __restrict__ fcw,
    const float* __restrict__ fcb, float* __restrict__ out){
  const int blk = blockIdx.x;
  const int b = blk / 3, cls = blk - b*3;
  const int lane = threadIdx.x;
  const float w0 = fcw[cls*2], w1 = fcw[cls*2 + 1], bb = fcb[cls];
  const float* hp = h2 + (long)b * T_ * 2;
  float l[32];
  float m = -1e30f;
  #pragma unroll
  for (int i = 0; i < 32; i++){
    int t = lane + 64*i;
    float2 hv = *(const float2*)(hp + t*2);
    l[i] = fmaf(hv.x, w0, fmaf(hv.y, w1, bb));
    m = fmaxf(m, l[i]);
  }
  #pragma unroll
  for (int s = 1; s < 64; s <<= 1) m = fmaxf(m, __shfl_xor(m, s));
  float sum = 0.f;
  #pragma unroll
  for (int i = 0; i < 32; i++){
    l[i] = fast_exp2((l[i] - m) * LOG2E);
    sum += l[i];
  }
  #pragma unroll
  for (int s = 1; s < 64; s <<= 1) sum += __shfl_xor(sum, s);
  float inv = 1.f / sum;
  float* ob = out + (long)b * T_ * 3 + cls;
  #pragma unroll
  for (int i = 0; i < 32; i++){
    int t = lane + 64*i;
    ob[(long)t * 3] = l[i] * inv;
  }
}

// ---------------------------------------------------------------- launch
extern "C" void kernel_launch(void* const* d_in, const int* in_sizes, int n_in,
                              void* d_out, int out_size, void* d_ws, size_t ws_size,
                              hipStream_t stream) {
  const float* x       = (const float*)d_in[0];
  const float* w_ih1_f = (const float*)d_in[1];
  const float* w_hh1_f = (const float*)d_in[2];
  const float* b1_f    = (const float*)d_in[3];
  const float* w_ih1_b = (const float*)d_in[4];
  const float* w_hh1_b = (const float*)d_in[5];
  const float* b1_b    = (const float*)d_in[6];
  const float* w_ih2_f = (const float*)d_in[7];
  const float* w_hh2_f = (const float*)d_in[8];
  const float* b2_f    = (const float*)d_in[9];
  const float* w_ih2_b = (const float*)d_in[10];
  const float* w_hh2_b = (const float*)d_in[11];
  const float* b2_b    = (const float*)d_in[12];
  const float* fc_w    = (const float*)d_in[13];
  const float* fc_b    = (const float*)d_in[14];
  float* out = (float*)d_out;
  float* ws  = (float*)d_ws;

  float* xg1   = ws + XG1_OFF;
  float* h1    = ws + H1_OFF;
  float* h2    = ws + H2_OFF;
  float* wpad  = ws + WPAD_OFF;
  float* bcomb = ws + BCOMB_OFF;

  prep_kernel<<<(128*152)/256, 256, 0, stream>>>(w_ih1_f, w_ih1_b, b1_f, b1_b, wpad, bcomb);
  xg1_kernel<<<(B_*T_)/64, 256, 0, stream>>>(x, wpad, bcomb, xg1);
  lstm1_kernel<<<B_*2, 64, 0, stream>>>(xg1, w_hh1_f, w_hh1_b, h1);
  lstm2_kernel<<<B_*2, 64, 0, stream>>>(h1, w_ih2_f, w_ih2_b, b2_f, b2_b,
                                        w_hh2_f, w_hh2_b, h2);
  head_kernel<<<B_*C_, 64, 0, stream>>>(h2, fc_w, fc_b, out);
}

// Round 2
// 853.601 us; speedup vs baseline: 1.1177x; 1.1177x over previous
//
#include <hip/hip_runtime.h>

static constexpr int B_ = 64, T_ = 2048, I_ = 150, C_ = 3;

// workspace layout (float offsets)
static constexpr long XG1_OFF   = 0;                       // B*T*128 = 16777216
static constexpr long H1_OFF    = 16777216;                // B*T*32  = 4194304
static constexpr long H2_OFF    = H1_OFF + 4194304;        // B*T*2   = 262144
static constexpr long WPAD_OFF  = H2_OFF + 262144;         // 128*152 = 19456
static constexpr long BCOMB_OFF = WPAD_OFF + 19456;        // 128

#define LOG2E 1.4426950408889634f

__device__ __forceinline__ float fast_exp2(float x){ return __builtin_amdgcn_exp2f(x); }
__device__ __forceinline__ float fast_rcp(float x){ return __builtin_amdgcn_rcpf(x); }
__device__ __forceinline__ float bcastlane(float v, int l){
  return __uint_as_float(__builtin_amdgcn_readlane(__float_as_uint(v), l));
}
// quad_perm broadcast of position P within each 4-lane quad (pure VALU DPP)
template<int P>
__device__ __forceinline__ float qb(float v){
  return __int_as_float(__builtin_amdgcn_mov_dpp(__float_as_int(v), P*0x55, 0xF, 0xF, true));
}

// ---------------------------------------------------------------- prep
// Padded/concatenated W_ih1 [128][152] (fwd gates 0..63, bwd 64..127) and
// combined bias[128], BOTH pre-scaled by -log2e (i,f,o rows) / -2log2e (g rows)
// so the recurrent kernels' transcendentals take exp2(s) directly.
__global__ void prep_kernel(const float* __restrict__ wf, const float* __restrict__ wb,
                            const float* __restrict__ bf, const float* __restrict__ bb,
                            float* __restrict__ wpad, float* __restrict__ bcomb){
  int idx = blockIdx.x * 256 + threadIdx.x;   // exactly 128*152 threads
  int g = idx / 152, k = idx - g * 152;
  int r = g & 63;
  float sc = ((r >> 4) == 2) ? (-2.f*LOG2E) : (-LOG2E);
  float v = 0.f;
  if (k < 150) v = (g < 64) ? wf[g*150 + k] : wb[(g-64)*150 + k];
  wpad[idx] = v * sc;
  if (idx < 128){
    int rr = idx & 63;
    float sb = ((rr >> 4) == 2) ? (-2.f*LOG2E) : (-LOG2E);
    bcomb[idx] = ((idx < 64) ? bf[idx] : bb[idx - 64]) * sb;
  }
}

// ---------------------------------------------------------------- xg1
// xg1[row][g] = bias[g] + sum_k x[row][k] * Wih[g][k] (pre-scaled weights)
__global__ void __launch_bounds__(256) xg1_kernel(
    const float* __restrict__ x, const float* __restrict__ wpad,
    const float* __restrict__ bcomb, float* __restrict__ xg){
  __shared__ float xs[64 * 156];          // pad 156: row stride % 32 banks != 0
  const int tid = threadIdx.x;
  const long rowbase = (long)blockIdx.x * 64;
  for (int idx = tid; idx < 64 * 150; idx += 256){
    int r = idx / 150;
    int k = idx - r * 150;
    xs[r*156 + k] = x[(rowbase + r)*150 + k];
  }
  __syncthreads();
  const int gg = tid & 15;    // gate group: gates gg*8 .. gg*8+7
  const int rr = tid >> 4;    // row group:  rows  rr*4 .. rr*4+3
  const float* wp  = wpad + gg*8*152;
  const float* xsp = xs + rr*4*156;
  float bias[8];
  #pragma unroll
  for (int i = 0; i < 8; i++) bias[i] = bcomb[gg*8 + i];
  float acc[4][8];
  #pragma unroll
  for (int r = 0; r < 4; r++)
    #pragma unroll
    for (int i = 0; i < 8; i++) acc[r][i] = bias[i];

  for (int k = 0; k < 148; k += 4){
    float4 xv[4], wv[8];
    #pragma unroll
    for (int r = 0; r < 4; r++) xv[r] = *(const float4*)(xsp + r*156 + k);
    #pragma unroll
    for (int i = 0; i < 8; i++) wv[i] = *(const float4*)(wp + i*152 + k);
    #pragma unroll
    for (int r = 0; r < 4; r++)
      #pragma unroll
      for (int i = 0; i < 8; i++){
        acc[r][i] = fmaf(xv[r].x, wv[i].x, acc[r][i]);
        acc[r][i] = fmaf(xv[r].y, wv[i].y, acc[r][i]);
        acc[r][i] = fmaf(xv[r].z, wv[i].z, acc[r][i]);
        acc[r][i] = fmaf(xv[r].w, wv[i].w, acc[r][i]);
      }
  }
  { // tail k = 148,149
    const int k = 148;
    float2 xv[4], wv[8];
    #pragma unroll
    for (int r = 0; r < 4; r++) xv[r] = *(const float2*)(xsp + r*156 + k);
    #pragma unroll
    for (int i = 0; i < 8; i++) wv[i] = *(const float2*)(wp + i*152 + k);
    #pragma unroll
    for (int r = 0; r < 4; r++)
      #pragma unroll
      for (int i = 0; i < 8; i++){
        acc[r][i] = fmaf(xv[r].x, wv[i].x, acc[r][i]);
        acc[r][i] = fmaf(xv[r].y, wv[i].y, acc[r][i]);
      }
  }
  #pragma unroll
  for (int r = 0; r < 4; r++){
    long row = rowbase + rr*4 + r;
    float4 o0 = make_float4(acc[r][0], acc[r][1], acc[r][2], acc[r][3]);
    float4 o1 = make_float4(acc[r][4], acc[r][5], acc[r][6], acc[r][7]);
    float4* dst = (float4*)(xg + row*128 + gg*8);
    dst[0] = o0; dst[1] = o1;
  }
}

// ---------------------------------------------------------------- lstm1
// One wave per (batch, dir). lane = 4*unit + gate. Gate gather via DPP
// quad_perm broadcast (no LDS). State c held scaled: c~ = -2log2e * c.
__global__ void __launch_bounds__(64) lstm1_kernel(
    const float* __restrict__ xg, const float* __restrict__ whf,
    const float* __restrict__ whb, float* __restrict__ h1){
  const int b = blockIdx.x >> 1, dir = blockIdx.x & 1, lane = threadIdx.x;
  const int g = lane & 3, u = lane >> 2;
  const int row = g*16 + u;                       // torch gate-major row
  const float* wh = dir ? whb : whf;
  const float ES = (g == 2) ? (-2.f*LOG2E) : (-LOG2E);
  float wrow[16];
  #pragma unroll
  for (int j = 0; j < 16; j++) wrow[j] = wh[row*16 + j] * ES;
  const float A  = (g == 2) ? (-4.f*LOG2E) : 1.f;   // g-gate: k*tanh folded
  const float Bc = (g == 2) ? ( 2.f*LOG2E) : 0.f;

  const float* xcol = xg + ((long)b * T_) * 128 + dir*64 + row;
  const int stride = dir ? -128 : 128;
  int coff = dir ? 2047*128 : 0;
  float* hptr = h1 + ((long)b*T_ + (dir ? 2047 : 0))*32 + dir*16 + u;
  const int hstride = dir ? -32 : 32;

  float h = 0.f, c = 0.f;                          // c is scaled state c~
  float xb0[8], xb1[8];
  #pragma unroll
  for (int uu = 0; uu < 8; uu++) xb0[uu] = xcol[coff + uu*stride];

  auto step = [&](float xgv){
    float a0 = xgv, a1 = 0.f, a2 = 0.f, a3 = 0.f;
    #pragma unroll
    for (int j = 0; j < 4; j++){
      a0 = fmaf(wrow[j],      bcastlane(h, 4*j),        a0);
      a1 = fmaf(wrow[j + 4],  bcastlane(h, 4*(j + 4)),  a1);
      a2 = fmaf(wrow[j + 8],  bcastlane(h, 4*(j + 8)),  a2);
      a3 = fmaf(wrow[j + 12], bcastlane(h, 4*(j + 12)), a3);
    }
    float s = (a0 + a1) + (a2 + a3);
    float act = fmaf(A, fast_rcp(1.f + fast_exp2(s)), Bc);
    float gi = qb<0>(act);
    float gf = qb<1>(act);
    float gG = qb<2>(act);   // = -2log2e * tanh(g_pre)
    float go = qb<3>(act);
    c = fmaf(gf, c, gi * gG);
    float th = fmaf(2.f, fast_rcp(1.f + fast_exp2(c)), -1.f);   // tanh(c_true)
    h = go * th;
    *hptr = h;               // 4 quad lanes store identical value
    hptr += hstride;
  };

  for (int cc = 0; cc < 128; ++cc){
    #pragma unroll
    for (int uu = 0; uu < 8; uu++) xb1[uu] = xcol[coff + (8 + uu)*stride];
    #pragma unroll
    for (int uu = 0; uu < 8; uu++) step(xb0[uu]);
    coff += 8*stride;
    if (cc < 127){
      #pragma unroll
      for (int uu = 0; uu < 8; uu++) xb0[uu] = xcol[coff + (8 + uu)*stride];
    }
    #pragma unroll
    for (int uu = 0; uu < 8; uu++) step(xb1[uu]);
    coff += 8*stride;
  }
}

// ---------------------------------------------------------------- lstm2
// One wave per (batch, dir). Phase A: 4-gate input projection -> LDS
// (pre-scaled). Phase B: serial H=1 scan, 2-deep register prefetch of xg2.
__global__ void __launch_bounds__(64) lstm2_kernel(
    const float* __restrict__ h1,
    const float* __restrict__ wi_f, const float* __restrict__ wi_b,
    const float* __restrict__ b_f,  const float* __restrict__ b_b,
    const float* __restrict__ u_f,  const float* __restrict__ u_b,
    float* __restrict__ h2){
  __shared__ float xg2raw[(T_ + 4) * 4];
  float* xg2 = xg2raw + 8;                  // valid t in [-2, 2049]
  const int b = blockIdx.x >> 1, dir = blockIdx.x & 1, lane = threadIdx.x;
  const float* wi = dir ? wi_b : wi_f;
  const float* bbp = dir ? b_b  : b_f;
  const float* uu = dir ? u_b  : u_f;
  const int g = lane & 3, tslot = lane >> 2;
  const float sc = (g == 2) ? (-2.f*LOG2E) : (-LOG2E);
  float4 wv[8];
  #pragma unroll
  for (int q = 0; q < 8; q++){
    float4 w = *(const float4*)(wi + g*32 + q*4);
    wv[q] = make_float4(w.x*sc, w.y*sc, w.z*sc, w.w*sc);
  }
  const float bg = bbp[g] * sc;
  const float* h1b = h1 + (long)b * T_ * 32;
  for (int i = 0; i < 128; i++){
    int t = tslot + 16*i;
    const float4* hr = (const float4*)(h1b + (long)t * 32);
    float a = bg;
    #pragma unroll
    for (int q = 0; q < 8; q++){
      float4 hv = hr[q];
      a = fmaf(hv.x, wv[q].x, a); a = fmaf(hv.y, wv[q].y, a);
      a = fmaf(hv.z, wv[q].z, a); a = fmaf(hv.w, wv[q].w, a);
    }
    xg2[t*4 + g] = a;
  }
  __syncthreads();
  const float u0 = uu[0] * (-LOG2E);
  const float u1 = uu[1] * (-LOG2E);
  const float u2 = uu[2] * (-2.f*LOG2E);
  const float u3 = uu[3] * (-LOG2E);
  const float A2 = -4.f*LOG2E, B2 = 2.f*LOG2E;
  float h = 0.f, c = 0.f;                    // c is scaled state c~
  float* outp = h2 + (long)b * T_ * 2 + dir;
  const int st = dir ? -1 : 1;
  int t = dir ? (T_ - 1) : 0;
  float4 xa = *(const float4*)&xg2[t*4];
  float4 xb = *(const float4*)&xg2[(t + st)*4];
  for (int n = 0; n < T_; n++){
    float4 xv = xa;
    xa = xb;
    xb = *(const float4*)&xg2[(t + 2*st)*4];  // padded region: garbage ok
    float gi = fast_rcp(1.f + fast_exp2(fmaf(u0, h, xv.x)));
    float gf = fast_rcp(1.f + fast_exp2(fmaf(u1, h, xv.y)));
    float gG = fmaf(A2, fast_rcp(1.f + fast_exp2(fmaf(u2, h, xv.z))), B2);
    float go = fast_rcp(1.f + fast_exp2(fmaf(u3, h, xv.w)));
    c = fmaf(gf, c, gi * gG);
    float th = fmaf(2.f, fast_rcp(1.f + fast_exp2(c)), -1.f);
    h = go * th;
    outp[(long)t * 2] = h;    // all lanes, same addr, same value
    t += st;
  }
}

// ---------------------------------------------------------------- head
// One wave per (batch, class): logits + softmax over T.
__global__ void __launch_bounds__(64) head_kernel(
    const float* __restrict__ h2, const float* __restrict__ fcw,
    const float* __restrict__ fcb, float* __restrict__ out){
  const int blk = blockIdx.x;
  const int b = blk / 3, cls = blk - b*3;
  const int lane = threadIdx.x;
  const float w0 = fcw[cls*2], w1 = fcw[cls*2 + 1], bb = fcb[cls];
  const float* hp = h2 + (long)b * T_ * 2;
  float l[32];
  float m = -1e30f;
  #pragma unroll
  for (int i = 0; i < 32; i++){
    int t = lane + 64*i;
    float2 hv = *(const float2*)(hp + t*2);
    l[i] = fmaf(hv.x, w0, fmaf(hv.y, w1, bb));
    m = fmaxf(m, l[i]);
  }
  #pragma unroll
  for (int s = 1; s < 64; s <<= 1) m = fmaxf(m, __shfl_xor(m, s));
  float sum = 0.f;
  #pragma unroll
  for (int i = 0; i < 32; i++){
    l[i] = fast_exp2((l[i] - m) * LOG2E);
    sum += l[i];
  }
  #pragma unroll
  for (int s = 1; s < 64; s <<= 1) sum += __shfl_xor(sum, s);
  float inv = 1.f / sum;
  float* ob = out + (long)b * T_ * 3 + cls;
  #pragma unroll
  for (int i = 0; i < 32; i++){
    int t = lane + 64*i;
    ob[(long)t * 3] = l[i] * inv;
  }
}

// ---------------------------------------------------------------- launch
extern "C" void kernel_launch(void* const* d_in, const int* in_sizes, int n_in,
                              void* d_out, int out_size, void* d_ws, size_t ws_size,
                              hipStream_t stream) {
  const float* x       = (const float*)d_in[0];
  const float* w_ih1_f = (const float*)d_in[1];
  const float* w_hh1_f = (const float*)d_in[2];
  const float* b1_f    = (const float*)d_in[3];
  const float* w_ih1_b = (const float*)d_in[4];
  const float* w_hh1_b = (const float*)d_in[5];
  const float* b1_b    = (const float*)d_in[6];
  const float* w_ih2_f = (const float*)d_in[7];
  const float* w_hh2_f = (const float*)d_in[8];
  const float* b2_f    = (const float*)d_in[9];
  const float* w_ih2_b = (const float*)d_in[10];
  const float* w_hh2_b = (const float*)d_in[11];
  const float* b2_b    = (const float*)d_in[12];
  const float* fc_w    = (const float*)d_in[13];
  const float* fc_b    = (const float*)d_in[14];
  float* out = (float*)d_out;
  float* ws  = (float*)d_ws;

  float* xg1   = ws + XG1_OFF;
  float* h1    = ws + H1_OFF;
  float* h2    = ws + H2_OFF;
  float* wpad  = ws + WPAD_OFF;
  float* bcomb = ws + BCOMB_OFF;

  prep_kernel<<<(128*152)/256, 256, 0, stream>>>(w_ih1_f, w_ih1_b, b1_f, b1_b, wpad, bcomb);
  xg1_kernel<<<(B_*T_)/64, 256, 0, stream>>>(x, wpad, bcomb, xg1);
  lstm1_kernel<<<B_*2, 64, 0, stream>>>(xg1, w_hh1_f, w_hh1_b, h1);
  lstm2_kernel<<<B_*2, 64, 0, stream>>>(h1, w_ih2_f, w_ih2_b, b2_f, b2_b,
                                        w_hh2_f, w_hh2_b, h2);
  head_kernel<<<B_*C_, 64, 0, stream>>>(h2, fc_w, fc_b, out);
}

// Round 4
// 770.691 us; speedup vs baseline: 1.2380x; 1.1076x over previous
//
#include <hip/hip_runtime.h>

static constexpr int B_ = 64, T_ = 2048, I_ = 150, C_ = 3;

// workspace layout (float offsets)
static constexpr long XG1_OFF   = 0;                       // B*T*128 = 16777216
static constexpr long H1_OFF    = 16777216;                // B*T*32  = 4194304
static constexpr long H2_OFF    = H1_OFF + 4194304;        // B*T*2   = 262144
static constexpr long WPAD_OFF  = H2_OFF + 262144;         // 128*152 = 19456
static constexpr long BCOMB_OFF = WPAD_OFF + 19456;        // 128

#define LOG2E 1.4426950408889634f

__device__ __forceinline__ float fast_exp2(float x){ return __builtin_amdgcn_exp2f(x); }
__device__ __forceinline__ float fast_rcp(float x){ return __builtin_amdgcn_rcpf(x); }
__device__ __forceinline__ float bcastlane(float v, int l){
  return __uint_as_float(__builtin_amdgcn_readlane(__float_as_uint(v), l));
}
// quad_perm broadcast of position P within each 4-lane quad (pure VALU DPP)
template<int P>
__device__ __forceinline__ float qb(float v){
  return __int_as_float(__builtin_amdgcn_mov_dpp(__float_as_int(v), P*0x55, 0xF, 0xF, true));
}

// ---------------------------------------------------------------- prep
__global__ void prep_kernel(const float* __restrict__ wf, const float* __restrict__ wb,
                            const float* __restrict__ bf, const float* __restrict__ bb,
                            float* __restrict__ wpad, float* __restrict__ bcomb){
  int idx = blockIdx.x * 256 + threadIdx.x;   // exactly 128*152 threads
  int g = idx / 152, k = idx - g * 152;
  int r = g & 63;
  float sc = ((r >> 4) == 2) ? (-2.f*LOG2E) : (-LOG2E);
  float v = 0.f;
  if (k < 150) v = (g < 64) ? wf[g*150 + k] : wb[(g-64)*150 + k];
  wpad[idx] = v * sc;
  if (idx < 128){
    int rr = idx & 63;
    float sb = ((rr >> 4) == 2) ? (-2.f*LOG2E) : (-LOG2E);
    bcomb[idx] = ((idx < 64) ? bf[idx] : bb[idx - 64]) * sb;
  }
}

// ---------------------------------------------------------------- xg1
__global__ void __launch_bounds__(256) xg1_kernel(
    const float* __restrict__ x, const float* __restrict__ wpad,
    const float* __restrict__ bcomb, float* __restrict__ xg){
  __shared__ float xs[64 * 156];          // pad 156: row stride % 32 banks != 0
  const int tid = threadIdx.x;
  const long rowbase = (long)blockIdx.x * 64;
  for (int idx = tid; idx < 64 * 150; idx += 256){
    int r = idx / 150;
    int k = idx - r * 150;
    xs[r*156 + k] = x[(rowbase + r)*150 + k];
  }
  __syncthreads();
  const int gg = tid & 15;    // gate group: gates gg*8 .. gg*8+7
  const int rr = tid >> 4;    // row group:  rows  rr*4 .. rr*4+3
  const float* wp  = wpad + gg*8*152;
  const float* xsp = xs + rr*4*156;
  float bias[8];
  #pragma unroll
  for (int i = 0; i < 8; i++) bias[i] = bcomb[gg*8 + i];
  float acc[4][8];
  #pragma unroll
  for (int r = 0; r < 4; r++)
    #pragma unroll
    for (int i = 0; i < 8; i++) acc[r][i] = bias[i];

  for (int k = 0; k < 148; k += 4){
    float4 xv[4], wv[8];
    #pragma unroll
    for (int r = 0; r < 4; r++) xv[r] = *(const float4*)(xsp + r*156 + k);
    #pragma unroll
    for (int i = 0; i < 8; i++) wv[i] = *(const float4*)(wp + i*152 + k);
    #pragma unroll
    for (int r = 0; r < 4; r++)
      #pragma unroll
      for (int i = 0; i < 8; i++){
        acc[r][i] = fmaf(xv[r].x, wv[i].x, acc[r][i]);
        acc[r][i] = fmaf(xv[r].y, wv[i].y, acc[r][i]);
        acc[r][i] = fmaf(xv[r].z, wv[i].z, acc[r][i]);
        acc[r][i] = fmaf(xv[r].w, wv[i].w, acc[r][i]);
      }
  }
  { // tail k = 148,149
    const int k = 148;
    float2 xv[4], wv[8];
    #pragma unroll
    for (int r = 0; r < 4; r++) xv[r] = *(const float2*)(xsp + r*156 + k);
    #pragma unroll
    for (int i = 0; i < 8; i++) wv[i] = *(const float2*)(wp + i*152 + k);
    #pragma unroll
    for (int r = 0; r < 4; r++)
      #pragma unroll
      for (int i = 0; i < 8; i++){
        acc[r][i] = fmaf(xv[r].x, wv[i].x, acc[r][i]);
        acc[r][i] = fmaf(xv[r].y, wv[i].y, acc[r][i]);
      }
  }
  #pragma unroll
  for (int r = 0; r < 4; r++){
    long row = rowbase + rr*4 + r;
    float4 o0 = make_float4(acc[r][0], acc[r][1], acc[r][2], acc[r][3]);
    float4 o1 = make_float4(acc[r][4], acc[r][5], acc[r][6], acc[r][7]);
    float4* dst = (float4*)(xg + row*128 + gg*8);
    dst[0] = o0; dst[1] = o1;
  }
}

// ---------------------------------------------------------------- lstm1
// One wave per (batch, dir). lane = 4*unit + gate. DPP gate gather.
// c held scaled: c~ = -2log2e*c. Stores batched: 1 coalesced store / 4 steps.
template<int DIR>
__device__ __forceinline__ void lstm1_body(
    const float* __restrict__ xg, const float* __restrict__ wh,
    float* __restrict__ h1, int b, int lane){
  const int g = lane & 3, u = lane >> 2;
  const int row = g*16 + u;                       // torch gate-major row
  const float ES = (g == 2) ? (-2.f*LOG2E) : (-LOG2E);
  float wrow[16];
  #pragma unroll
  for (int j = 0; j < 16; j++) wrow[j] = wh[row*16 + j] * ES;
  const float A  = (g == 2) ? (-4.f*LOG2E) : 1.f;   // g-gate: k*tanh folded
  const float Bc = (g == 2) ? ( 2.f*LOG2E) : 0.f;

  constexpr int stride = DIR ? -128 : 128;
  constexpr int hstr   = DIR ? -32  : 32;
  const float* xcol = xg + ((long)b*T_ + (DIR ? 2047 : 0))*128 + DIR*64 + row;
  // lane (u,g) stores h(t0 + g*dirsign) for unit u at column DIR*16 + u
  float* hptr = h1 + ((long)b*T_ + (DIR ? 2047 : 0))*32 + DIR*16 + u + (long)g*hstr;

  const bool s0m = (g & 1) != 0;
  const bool s1m = (g & 2) != 0;

  float h = 0.f, c = 0.f;                          // c is scaled state c~
  float xb0[8], xb1[8];
  #pragma unroll
  for (int k = 0; k < 8; k++) xb0[k] = xcol[k*stride];

  auto step = [&](float xgv){
    float a0 = xgv, a1 = 0.f, a2 = 0.f, a3 = 0.f;
    #pragma unroll
    for (int j = 0; j < 4; j++){
      a0 = fmaf(wrow[j],      bcastlane(h, 4*j),        a0);
      a1 = fmaf(wrow[j + 4],  bcastlane(h, 4*(j + 4)),  a1);
      a2 = fmaf(wrow[j + 8],  bcastlane(h, 4*(j + 8)),  a2);
      a3 = fmaf(wrow[j + 12], bcastlane(h, 4*(j + 12)), a3);
    }
    float s = (a0 + a1) + (a2 + a3);
    float act = fmaf(A, fast_rcp(1.f + fast_exp2(s)), Bc);
    float gi = qb<0>(act);
    float gf = qb<1>(act);
    float gG = qb<2>(act);   // = -2log2e * tanh(g_pre)
    float go = qb<3>(act);
    c = fmaf(gf, c, gi * gG);
    h = go * fmaf(2.f, fast_rcp(1.f + fast_exp2(c)), -1.f);
  };
  auto quad = [&](float x0, float x1, float x2, float x3){
    step(x0); float hA = h;
    step(x1); float hB = h;
    step(x2); float hC = h;
    step(x3); float hD = h;
    float p0 = s0m ? hB : hA;
    float p1 = s0m ? hD : hC;
    *hptr = s1m ? p1 : p0;
    hptr += 4*hstr;
  };

  for (int cc = 0; cc < 128; ++cc){
    #pragma unroll
    for (int k = 0; k < 8; k++) xb1[k] = xcol[(8 + k)*stride];
    quad(xb0[0], xb0[1], xb0[2], xb0[3]);
    quad(xb0[4], xb0[5], xb0[6], xb0[7]);
    xcol += 8*stride;
    if (cc < 127){
      #pragma unroll
      for (int k = 0; k < 8; k++) xb0[k] = xcol[(8 + k)*stride];
    }
    quad(xb1[0], xb1[1], xb1[2], xb1[3]);
    quad(xb1[4], xb1[5], xb1[6], xb1[7]);
    xcol += 8*stride;
  }
}

__global__ void __launch_bounds__(64) lstm1_kernel(
    const float* __restrict__ xg, const float* __restrict__ whf,
    const float* __restrict__ whb, float* __restrict__ h1){
  const int b = blockIdx.x >> 1, dir = blockIdx.x & 1, lane = threadIdx.x;
  if (dir) lstm1_body<1>(xg, whb, h1, b, lane);
  else     lstm1_body<0>(xg, whf, h1, b, lane);
}

// ---------------------------------------------------------------- lstm2
// Phase A: 4-gate input projection -> LDS (pre-scaled).
// Phase B: serial H=1 scan; 8-deep LDS prefetch; 1 store / 8 steps (lanes 0-7).
template<int DIR>
__device__ __forceinline__ void lstm2_phaseB(
    const float* __restrict__ xg2, const float* __restrict__ uu,
    float* __restrict__ h2, int b, int lane){
  const float u0 = uu[0] * (-LOG2E);
  const float u1 = uu[1] * (-LOG2E);
  const float u2 = uu[2] * (-2.f*LOG2E);
  const float u3 = uu[3] * (-LOG2E);
  const float A2 = -4.f*LOG2E, B2 = 2.f*LOG2E;
  constexpr int st = DIR ? -1 : 1;
  const float* xp = xg2 + (DIR ? 2047*4 : 0);
  float* p = h2 + ((long)b*T_ + (DIR ? 2047 : 0))*2 + DIR + (long)lane*2*st;
  const bool b0 = (lane & 1) != 0, b1 = (lane & 2) != 0, b2 = (lane & 4) != 0;
  const bool do_st = lane < 8;

  float h = 0.f, c = 0.f;                    // c is scaled state c~
  float4 Aq[8], Bq[8];
  #pragma unroll
  for (int k = 0; k < 8; k++) Aq[k] = *(const float4*)(xp + 4*st*k);

  auto step = [&](float4 xv)->float{
    float gi = fast_rcp(1.f + fast_exp2(fmaf(u0, h, xv.x)));
    float gf = fast_rcp(1.f + fast_exp2(fmaf(u1, h, xv.y)));
    float gG = fmaf(A2, fast_rcp(1.f + fast_exp2(fmaf(u2, h, xv.z))), B2);
    float go = fast_rcp(1.f + fast_exp2(fmaf(u3, h, xv.w)));
    c = fmaf(gf, c, gi * gG);
    h = go * fmaf(2.f, fast_rcp(1.f + fast_exp2(c)), -1.f);
    return h;
  };
  auto oct = [&](float4* X){
    float h0v = step(X[0]), h1v = step(X[1]), h2v = step(X[2]), h3v = step(X[3]);
    float h4v = step(X[4]), h5v = step(X[5]), h6v = step(X[6]), h7v = step(X[7]);
    float q0 = b0 ? h1v : h0v;
    float q1 = b0 ? h3v : h2v;
    float q2 = b0 ? h5v : h4v;
    float q3 = b0 ? h7v : h6v;
    float r0 = b1 ? q1 : q0;
    float r1 = b1 ? q3 : q2;
    float sv = b2 ? r1 : r0;
    if (do_st) *p = sv;        // lanes 0-7: coalesced 8-step store
    p += 16*st;
  };

  for (int cc = 0; cc < 128; ++cc){
    #pragma unroll
    for (int k = 0; k < 8; k++) Bq[k] = *(const float4*)(xp + 4*st*(8 + k));
    oct(Aq);
    xp += 32*st;
    if (cc < 127){
      #pragma unroll
      for (int k = 0; k < 8; k++) Aq[k] = *(const float4*)(xp + 4*st*(8 + k));
    }
    oct(Bq);
    xp += 32*st;
  }
}

__global__ void __launch_bounds__(64) lstm2_kernel(
    const float* __restrict__ h1,
    const float* __restrict__ wi_f, const float* __restrict__ wi_b,
    const float* __restrict__ b_f,  const float* __restrict__ b_b,
    const float* __restrict__ u_f,  const float* __restrict__ u_b,
    float* __restrict__ h2){
  __shared__ float xg2[T_ * 4];
  const int b = blockIdx.x >> 1, dir = blockIdx.x & 1, lane = threadIdx.x;
  const float* wi = dir ? wi_b : wi_f;
  const float* bbp = dir ? b_b  : b_f;
  const float* uu = dir ? u_b  : u_f;
  const int g = lane & 3, tslot = lane >> 2;
  const float sc = (g == 2) ? (-2.f*LOG2E) : (-LOG2E);
  float4 wv[8];
  #pragma unroll
  for (int q = 0; q < 8; q++){
    float4 w = *(const float4*)(wi + g*32 + q*4);
    wv[q] = make_float4(w.x*sc, w.y*sc, w.z*sc, w.w*sc);
  }
  const float bg = bbp[g] * sc;
  const float* h1b = h1 + (long)b * T_ * 32;
  for (int i = 0; i < 128; i++){
    int t = tslot + 16*i;
    const float4* hr = (const float4*)(h1b + (long)t * 32);
    float a = bg;
    #pragma unroll
    for (int q = 0; q < 8; q++){
      float4 hv = hr[q];
      a = fmaf(hv.x, wv[q].x, a); a = fmaf(hv.y, wv[q].y, a);
      a = fmaf(hv.z, wv[q].z, a); a = fmaf(hv.w, wv[q].w, a);
    }
    xg2[t*4 + g] = a;
  }
  __syncthreads();
  if (dir) lstm2_phaseB<1>(xg2, uu, h2, b, lane);
  else     lstm2_phaseB<0>(xg2, uu, h2, b, lane);
}

// ---------------------------------------------------------------- head
__global__ void __launch_bounds__(64) head_kernel(
    const float* __restrict__ h2, const float* __restrict__ fcw,
    const float* __restrict__ fcb, float* __restrict__ out){
  const int blk = blockIdx.x;
  const int b = blk / 3, cls = blk - b*3;
  const int lane = threadIdx.x;
  const float w0 = fcw[cls*2], w1 = fcw[cls*2 + 1], bb = fcb[cls];
  const float* hp = h2 + (long)b * T_ * 2;
  float l[32];
  float m = -1e30f;
  #pragma unroll
  for (int i = 0; i < 32; i++){
    int t = lane + 64*i;
    float2 hv = *(const float2*)(hp + t*2);
    l[i] = fmaf(hv.x, w0, fmaf(hv.y, w1, bb));
    m = fmaxf(m, l[i]);
  }
  #pragma unroll
  for (int s = 1; s < 64; s <<= 1) m = fmaxf(m, __shfl_xor(m, s));
  float sum = 0.f;
  #pragma unroll
  for (int i = 0; i < 32; i++){
    l[i] = fast_exp2((l[i] - m) * LOG2E);
    sum += l[i];
  }
  #pragma unroll
  for (int s = 1; s < 64; s <<= 1) sum += __shfl_xor(sum, s);
  float inv = 1.f / sum;
  float* ob = out + (long)b * T_ * 3 + cls;
  #pragma unroll
  for (int i = 0; i < 32; i++){
    int t = lane + 64*i;
    ob[(long)t * 3] = l[i] * inv;
  }
}

// ---------------------------------------------------------------- launch
extern "C" void kernel_launch(void* const* d_in, const int* in_sizes, int n_in,
                              void* d_out, int out_size, void* d_ws, size_t ws_size,
                              hipStream_t stream) {
  const float* x       = (const float*)d_in[0];
  const float* w_ih1_f = (const float*)d_in[1];
  const float* w_hh1_f = (const float*)d_in[2];
  const float* b1_f    = (const float*)d_in[3];
  const float* w_ih1_b = (const float*)d_in[4];
  const float* w_hh1_b = (const float*)d_in[5];
  const float* b1_b    = (const float*)d_in[6];
  const float* w_ih2_f = (const float*)d_in[7];
  const float* w_hh2_f = (const float*)d_in[8];
  const float* b2_f    = (const float*)d_in[9];
  const float* w_ih2_b = (const float*)d_in[10];
  const float* w_hh2_b = (const float*)d_in[11];
  const float* b2_b    = (const float*)d_in[12];
  const float* fc_w    = (const float*)d_in[13];
  const float* fc_b    = (const float*)d_in[14];
  float* out = (float*)d_out;
  float* ws  = (float*)d_ws;

  float* xg1   = ws + XG1_OFF;
  float* h1    = ws + H1_OFF;
  float* h2    = ws + H2_OFF;
  float* wpad  = ws + WPAD_OFF;
  float* bcomb = ws + BCOMB_OFF;

  prep_kernel<<<(128*152)/256, 256, 0, stream>>>(w_ih1_f, w_ih1_b, b1_f, b1_b, wpad, bcomb);
  xg1_kernel<<<(B_*T_)/64, 256, 0, stream>>>(x, wpad, bcomb, xg1);
  lstm1_kernel<<<B_*2, 64, 0, stream>>>(xg1, w_hh1_f, w_hh1_b, h1);
  lstm2_kernel<<<B_*2, 64, 0, stream>>>(h1, w_ih2_f, w_ih2_b, b2_f, b2_b,
                                        w_hh2_f, w_hh2_b, h2);
  head_kernel<<<B_*C_, 64, 0, stream>>>(h2, fc_w, fc_b, out);
}

// Round 5
// 406.882 us; speedup vs baseline: 2.3449x; 1.8941x over previous
//
#include <hip/hip_runtime.h>

static constexpr int B_ = 64, T_ = 2048, I_ = 150, C_ = 3;

// chunked-scan parameters: 16 chunks x 128 steps, 96-step warm-start
static constexpr int NCHUNK = 16, CHUNK = 128, WARM_HALF_ITERS = 6; // 6*16=96 steps

// workspace layout (float offsets)
static constexpr long XG1_OFF   = 0;                       // B*T*128 = 16777216
static constexpr long H1_OFF    = 16777216;                // B*T*32  = 4194304
static constexpr long H2_OFF    = H1_OFF + 4194304;        // B*T*2   = 262144
static constexpr long WPAD_OFF  = H2_OFF + 262144;         // 128*152 = 19456
static constexpr long BCOMB_OFF = WPAD_OFF + 19456;        // 128

#define LOG2E 1.4426950408889634f

__device__ __forceinline__ float fast_exp2(float x){ return __builtin_amdgcn_exp2f(x); }
__device__ __forceinline__ float fast_rcp(float x){ return __builtin_amdgcn_rcpf(x); }
__device__ __forceinline__ float bcastlane(float v, int l){
  return __uint_as_float(__builtin_amdgcn_readlane(__float_as_uint(v), l));
}
// quad_perm broadcast of position P within each 4-lane quad (pure VALU DPP)
template<int P>
__device__ __forceinline__ float qb(float v){
  return __int_as_float(__builtin_amdgcn_mov_dpp(__float_as_int(v), P*0x55, 0xF, 0xF, true));
}

// ---------------------------------------------------------------- prep
__global__ void prep_kernel(const float* __restrict__ wf, const float* __restrict__ wb,
                            const float* __restrict__ bf, const float* __restrict__ bb,
                            float* __restrict__ wpad, float* __restrict__ bcomb){
  int idx = blockIdx.x * 256 + threadIdx.x;   // exactly 128*152 threads
  int g = idx / 152, k = idx - g * 152;
  int r = g & 63;
  float sc = ((r >> 4) == 2) ? (-2.f*LOG2E) : (-LOG2E);
  float v = 0.f;
  if (k < 150) v = (g < 64) ? wf[g*150 + k] : wb[(g-64)*150 + k];
  wpad[idx] = v * sc;
  if (idx < 128){
    int rr = idx & 63;
    float sb = ((rr >> 4) == 2) ? (-2.f*LOG2E) : (-LOG2E);
    bcomb[idx] = ((idx < 64) ? bf[idx] : bb[idx - 64]) * sb;
  }
}

// ---------------------------------------------------------------- xg1
__global__ void __launch_bounds__(256) xg1_kernel(
    const float* __restrict__ x, const float* __restrict__ wpad,
    const float* __restrict__ bcomb, float* __restrict__ xg){
  __shared__ float xs[64 * 156];          // pad 156: row stride % 32 banks != 0
  const int tid = threadIdx.x;
  const long rowbase = (long)blockIdx.x * 64;
  for (int idx = tid; idx < 64 * 150; idx += 256){
    int r = idx / 150;
    int k = idx - r * 150;
    xs[r*156 + k] = x[(rowbase + r)*150 + k];
  }
  __syncthreads();
  const int gg = tid & 15;    // gate group: gates gg*8 .. gg*8+7
  const int rr = tid >> 4;    // row group:  rows  rr*4 .. rr*4+3
  const float* wp  = wpad + gg*8*152;
  const float* xsp = xs + rr*4*156;
  float bias[8];
  #pragma unroll
  for (int i = 0; i < 8; i++) bias[i] = bcomb[gg*8 + i];
  float acc[4][8];
  #pragma unroll
  for (int r = 0; r < 4; r++)
    #pragma unroll
    for (int i = 0; i < 8; i++) acc[r][i] = bias[i];

  for (int k = 0; k < 148; k += 4){
    float4 xv[4], wv[8];
    #pragma unroll
    for (int r = 0; r < 4; r++) xv[r] = *(const float4*)(xsp + r*156 + k);
    #pragma unroll
    for (int i = 0; i < 8; i++) wv[i] = *(const float4*)(wp + i*152 + k);
    #pragma unroll
    for (int r = 0; r < 4; r++)
      #pragma unroll
      for (int i = 0; i < 8; i++){
        acc[r][i] = fmaf(xv[r].x, wv[i].x, acc[r][i]);
        acc[r][i] = fmaf(xv[r].y, wv[i].y, acc[r][i]);
        acc[r][i] = fmaf(xv[r].z, wv[i].z, acc[r][i]);
        acc[r][i] = fmaf(xv[r].w, wv[i].w, acc[r][i]);
      }
  }
  { // tail k = 148,149
    const int k = 148;
    float2 xv[4], wv[8];
    #pragma unroll
    for (int r = 0; r < 4; r++) xv[r] = *(const float2*)(xsp + r*156 + k);
    #pragma unroll
    for (int i = 0; i < 8; i++) wv[i] = *(const float2*)(wp + i*152 + k);
    #pragma unroll
    for (int r = 0; r < 4; r++)
      #pragma unroll
      for (int i = 0; i < 8; i++){
        acc[r][i] = fmaf(xv[r].x, wv[i].x, acc[r][i]);
        acc[r][i] = fmaf(xv[r].y, wv[i].y, acc[r][i]);
      }
  }
  #pragma unroll
  for (int r = 0; r < 4; r++){
    long row = rowbase + rr*4 + r;
    float4 o0 = make_float4(acc[r][0], acc[r][1], acc[r][2], acc[r][3]);
    float4 o1 = make_float4(acc[r][4], acc[r][5], acc[r][6], acc[r][7]);
    float4* dst = (float4*)(xg + row*128 + gg*8);
    dst[0] = o0; dst[1] = o1;
  }
}

// ---------------------------------------------------------------- lstm1
// One wave per (batch, dir, chunk). lane = 4*unit + gate. DPP gate gather.
// c held scaled: c~ = -2log2e*c. 96-step zero-state warmup, 128-step emit.
template<int DIR>
__device__ __forceinline__ void lstm1_body(
    const float* __restrict__ xg, const float* __restrict__ wh,
    float* __restrict__ h1, int b, int chunk, int lane){
  const int g = lane & 3, u = lane >> 2;
  const int row = g*16 + u;                       // torch gate-major row
  const float ES = (g == 2) ? (-2.f*LOG2E) : (-LOG2E);
  float wrow[16];
  #pragma unroll
  for (int j = 0; j < 16; j++) wrow[j] = wh[row*16 + j] * ES;
  const float A  = (g == 2) ? (-4.f*LOG2E) : 1.f;   // g-gate: k*tanh folded
  const float Bc = (g == 2) ? ( 2.f*LOG2E) : 0.f;

  constexpr int stride = DIR ? -128 : 128;
  constexpr int hstr   = DIR ? -32  : 32;
  const int warm_half = (chunk == 0) ? 0 : WARM_HALF_ITERS;  // 16 steps per iter
  const int it = warm_half + 8;                              // 8 iters emit = 128 steps
  const int warm = warm_half * 16;
  const long tb = DIR ? (2047L - (long)CHUNK*chunk + warm)
                      : ((long)CHUNK*chunk - warm);

  const float* xcol = xg + ((long)b*T_ + tb)*128 + DIR*64 + row;
  float* hptr = h1 + ((long)b*T_ + tb)*32 + DIR*16 + u + (long)g*hstr;

  const bool s0m = (g & 1) != 0;
  const bool s1m = (g & 2) != 0;

  float h = 0.f, c = 0.f;                          // c is scaled state c~
  float xb0[8], xb1[8];
  #pragma unroll
  for (int k = 0; k < 8; k++) xb0[k] = xcol[k*stride];

  auto step = [&](float xgv){
    float a0 = xgv, a1 = 0.f, a2 = 0.f, a3 = 0.f;
    #pragma unroll
    for (int j = 0; j < 4; j++){
      a0 = fmaf(wrow[j],      bcastlane(h, 4*j),        a0);
      a1 = fmaf(wrow[j + 4],  bcastlane(h, 4*(j + 4)),  a1);
      a2 = fmaf(wrow[j + 8],  bcastlane(h, 4*(j + 8)),  a2);
      a3 = fmaf(wrow[j + 12], bcastlane(h, 4*(j + 12)), a3);
    }
    float s = (a0 + a1) + (a2 + a3);
    float act = fmaf(A, fast_rcp(1.f + fast_exp2(s)), Bc);
    float gi = qb<0>(act);
    float gf = qb<1>(act);
    float gG = qb<2>(act);   // = -2log2e * tanh(g_pre)
    float go = qb<3>(act);
    c = fmaf(gf, c, gi * gG);
    h = go * fmaf(2.f, fast_rcp(1.f + fast_exp2(c)), -1.f);
  };
  auto quad = [&](float x0, float x1, float x2, float x3, bool st){
    step(x0); float hA = h;
    step(x1); float hB = h;
    step(x2); float hC = h;
    step(x3); float hD = h;
    float p0 = s0m ? hB : hA;
    float p1 = s0m ? hD : hC;
    if (st) *hptr = s1m ? p1 : p0;   // lane(u,g): h(t0+g*dirsign), unit u
    hptr += 4*hstr;
  };

  for (int i = 0; i < it; ++i){
    const bool st = (i >= warm_half);
    #pragma unroll
    for (int k = 0; k < 8; k++) xb1[k] = xcol[(8 + k)*stride];
    quad(xb0[0], xb0[1], xb0[2], xb0[3], st);
    quad(xb0[4], xb0[5], xb0[6], xb0[7], st);
    xcol += 8*stride;
    if (i < it - 1){
      #pragma unroll
      for (int k = 0; k < 8; k++) xb0[k] = xcol[(8 + k)*stride];
    }
    quad(xb1[0], xb1[1], xb1[2], xb1[3], st);
    quad(xb1[4], xb1[5], xb1[6], xb1[7], st);
    xcol += 8*stride;
  }
}

__global__ void __launch_bounds__(64) lstm1_kernel(
    const float* __restrict__ xg, const float* __restrict__ whf,
    const float* __restrict__ whb, float* __restrict__ h1){
  const int chunk = blockIdx.x & (NCHUNK - 1);
  const int pair  = blockIdx.x >> 4;
  const int b = pair >> 1, dir = pair & 1, lane = threadIdx.x;
  if (dir) lstm1_body<1>(xg, whb, h1, b, chunk, lane);
  else     lstm1_body<0>(xg, whf, h1, b, chunk, lane);
}

// ---------------------------------------------------------------- lstm2
// One wave per (batch, dir, chunk). Phase A: projection of the chunk window
// (in processing order) -> LDS. Phase B: serial H=1 scan with warmup.
template<int DIR>
__device__ __forceinline__ void lstm2_phaseB(
    const float* __restrict__ xg2, const float* __restrict__ uu,
    float* __restrict__ h2, int b, long tb, int warm_half, int nit, int lane){
  const float u0 = uu[0] * (-LOG2E);
  const float u1 = uu[1] * (-LOG2E);
  const float u2 = uu[2] * (-2.f*LOG2E);
  const float u3 = uu[3] * (-LOG2E);
  const float A2 = -4.f*LOG2E, B2 = 2.f*LOG2E;
  constexpr int stsg = DIR ? -1 : 1;
  const float* xp = xg2;                       // processing order, ascending
  float* p = h2 + ((long)b*T_ + tb)*2 + DIR + (long)lane*2*stsg;
  const bool b0 = (lane & 1) != 0, b1 = (lane & 2) != 0, b2 = (lane & 4) != 0;
  const bool lane_st = lane < 8;

  float h = 0.f, c = 0.f;                      // c is scaled state c~
  float4 Aq[8], Bq[8];
  #pragma unroll
  for (int k = 0; k < 8; k++) Aq[k] = *(const float4*)(xp + 4*k);

  auto step = [&](float4 xv)->float{
    float gi = fast_rcp(1.f + fast_exp2(fmaf(u0, h, xv.x)));
    float gf = fast_rcp(1.f + fast_exp2(fmaf(u1, h, xv.y)));
    float gG = fmaf(A2, fast_rcp(1.f + fast_exp2(fmaf(u2, h, xv.z))), B2);
    float go = fast_rcp(1.f + fast_exp2(fmaf(u3, h, xv.w)));
    c = fmaf(gf, c, gi * gG);
    h = go * fmaf(2.f, fast_rcp(1.f + fast_exp2(c)), -1.f);
    return h;
  };
  auto oct = [&](float4* X, bool st){
    float h0v = step(X[0]), h1v = step(X[1]), h2v = step(X[2]), h3v = step(X[3]);
    float h4v = step(X[4]), h5v = step(X[5]), h6v = step(X[6]), h7v = step(X[7]);
    float q0 = b0 ? h1v : h0v;
    float q1 = b0 ? h3v : h2v;
    float q2 = b0 ? h5v : h4v;
    float q3 = b0 ? h7v : h6v;
    float r0 = b1 ? q1 : q0;
    float r1 = b1 ? q3 : q2;
    float sv = b2 ? r1 : r0;
    if (st && lane_st) *p = sv;    // lanes 0-7: coalesced 8-step store
    p += 16*stsg;
  };

  for (int i = 0; i < nit; ++i){
    const bool st = (i >= warm_half);
    #pragma unroll
    for (int k = 0; k < 8; k++) Bq[k] = *(const float4*)(xp + 4*(8 + k));
    oct(Aq, st);
    xp += 32;
    if (i < nit - 1){
      #pragma unroll
      for (int k = 0; k < 8; k++) Aq[k] = *(const float4*)(xp + 4*(8 + k));
    }
    oct(Bq, st);
    xp += 32;
  }
}

__global__ void __launch_bounds__(64) lstm2_kernel(
    const float* __restrict__ h1,
    const float* __restrict__ wi_f, const float* __restrict__ wi_b,
    const float* __restrict__ b_f,  const float* __restrict__ b_b,
    const float* __restrict__ u_f,  const float* __restrict__ u_b,
    float* __restrict__ h2){
  __shared__ float xg2[(WARM_HALF_ITERS*16 + CHUNK) * 4];   // 224*4 floats
  const int chunk = blockIdx.x & (NCHUNK - 1);
  const int pair  = blockIdx.x >> 4;
  const int b = pair >> 1, dir = pair & 1, lane = threadIdx.x;
  const float* wi  = dir ? wi_b : wi_f;
  const float* bbp = dir ? b_b  : b_f;
  const float* uu  = dir ? u_b  : u_f;
  const int warm_half = (chunk == 0) ? 0 : WARM_HALF_ITERS;
  const int nit = warm_half + 8;
  const int warm = warm_half * 16;
  const long tb = dir ? (2047L - (long)CHUNK*chunk + warm)
                      : ((long)CHUNK*chunk - warm);
  const int g = lane & 3, tslot = lane >> 2;
  const float sc = (g == 2) ? (-2.f*LOG2E) : (-LOG2E);
  float4 wv[8];
  #pragma unroll
  for (int q = 0; q < 8; q++){
    float4 w = *(const float4*)(wi + g*32 + q*4);
    wv[q] = make_float4(w.x*sc, w.y*sc, w.z*sc, w.w*sc);
  }
  const float bg = bbp[g] * sc;
  const float* h1b = h1 + (long)b * T_ * 32;
  for (int i = 0; i < nit; i++){
    int s = tslot + 16*i;                 // local step in processing order
    long t = dir ? (tb - s) : (tb + s);
    const float4* hr = (const float4*)(h1b + t * 32);
    float a = bg;
    #pragma unroll
    for (int q = 0; q < 8; q++){
      float4 hv = hr[q];
      a = fmaf(hv.x, wv[q].x, a); a = fmaf(hv.y, wv[q].y, a);
      a = fmaf(hv.z, wv[q].z, a); a = fmaf(hv.w, wv[q].w, a);
    }
    xg2[s*4 + g] = a;
  }
  __syncthreads();
  if (dir) lstm2_phaseB<1>(xg2, uu, h2, b, tb, warm_half, nit, lane);
  else     lstm2_phaseB<0>(xg2, uu, h2, b, tb, warm_half, nit, lane);
}

// ---------------------------------------------------------------- head
__global__ void __launch_bounds__(64) head_kernel(
    const float* __restrict__ h2, const float* __restrict__ fcw,
    const float* __restrict__ fcb, float* __restrict__ out){
  const int blk = blockIdx.x;
  const int b = blk / 3, cls = blk - b*3;
  const int lane = threadIdx.x;
  const float w0 = fcw[cls*2], w1 = fcw[cls*2 + 1], bb = fcb[cls];
  const float* hp = h2 + (long)b * T_ * 2;
  float l[32];
  float m = -1e30f;
  #pragma unroll
  for (int i = 0; i < 32; i++){
    int t = lane + 64*i;
    float2 hv = *(const float2*)(hp + t*2);
    l[i] = fmaf(hv.x, w0, fmaf(hv.y, w1, bb));
    m = fmaxf(m, l[i]);
  }
  #pragma unroll
  for (int s = 1; s < 64; s <<= 1) m = fmaxf(m, __shfl_xor(m, s));
  float sum = 0.f;
  #pragma unroll
  for (int i = 0; i < 32; i++){
    l[i] = fast_exp2((l[i] - m) * LOG2E);
    sum += l[i];
  }
  #pragma unroll
  for (int s = 1; s < 64; s <<= 1) sum += __shfl_xor(sum, s);
  float inv = 1.f / sum;
  float* ob = out + (long)b * T_ * 3 + cls;
  #pragma unroll
  for (int i = 0; i < 32; i++){
    int t = lane + 64*i;
    ob[(long)t * 3] = l[i] * inv;
  }
}

// ---------------------------------------------------------------- launch
extern "C" void kernel_launch(void* const* d_in, const int* in_sizes, int n_in,
                              void* d_out, int out_size, void* d_ws, size_t ws_size,
                              hipStream_t stream) {
  const float* x       = (const float*)d_in[0];
  const float* w_ih1_f = (const float*)d_in[1];
  const float* w_hh1_f = (const float*)d_in[2];
  const float* b1_f    = (const float*)d_in[3];
  const float* w_ih1_b = (const float*)d_in[4];
  const float* w_hh1_b = (const float*)d_in[5];
  const float* b1_b    = (const float*)d_in[6];
  const float* w_ih2_f = (const float*)d_in[7];
  const float* w_hh2_f = (const float*)d_in[8];
  const float* b2_f    = (const float*)d_in[9];
  const float* w_ih2_b = (const float*)d_in[10];
  const float* w_hh2_b = (const float*)d_in[11];
  const float* b2_b    = (const float*)d_in[12];
  const float* fc_w    = (const float*)d_in[13];
  const float* fc_b    = (const float*)d_in[14];
  float* out = (float*)d_out;
  float* ws  = (float*)d_ws;

  float* xg1   = ws + XG1_OFF;
  float* h1    = ws + H1_OFF;
  float* h2    = ws + H2_OFF;
  float* wpad  = ws + WPAD_OFF;
  float* bcomb = ws + BCOMB_OFF;

  prep_kernel<<<(128*152)/256, 256, 0, stream>>>(w_ih1_f, w_ih1_b, b1_f, b1_b, wpad, bcomb);
  xg1_kernel<<<(B_*T_)/64, 256, 0, stream>>>(x, wpad, bcomb, xg1);
  lstm1_kernel<<<B_*2*NCHUNK, 64, 0, stream>>>(xg1, w_hh1_f, w_hh1_b, h1);
  lstm2_kernel<<<B_*2*NCHUNK, 64, 0, stream>>>(h1, w_ih2_f, w_ih2_b, b2_f, b2_b,
                                               w_hh2_f, w_hh2_b, h2);
  head_kernel<<<B_*C_, 64, 0, stream>>>(h2, fc_w, fc_b, out);
}

// Round 6
// 193.229 us; speedup vs baseline: 4.9377x; 2.1057x over previous
//
#include <hip/hip_runtime.h>

static constexpr int B_ = 64, T_ = 2048, I_ = 150, C_ = 3;

// chunked-scan parameters: 16 chunks x 128 steps, 96-step warm-start
static constexpr int NCHUNK = 16, CHUNK = 128, WARM_HALF_ITERS = 6; // 6*16=96 steps

// workspace layout (float offsets)
static constexpr long XG1_OFF   = 0;                       // B*T*128 = 16777216
static constexpr long H1_OFF    = 16777216;                // B*T*32  = 4194304
static constexpr long H2_OFF    = H1_OFF + 4194304;        // B*T*2   = 262144
static constexpr long WPAD_OFF  = H2_OFF + 262144;         // 128*152 = 19456
static constexpr long BCOMB_OFF = WPAD_OFF + 19456;        // 128

#define LOG2E 1.4426950408889634f

__device__ __forceinline__ float fast_exp2(float x){ return __builtin_amdgcn_exp2f(x); }
__device__ __forceinline__ float fast_rcp(float x){ return __builtin_amdgcn_rcpf(x); }
__device__ __forceinline__ float bcastlane(float v, int l){
  return __uint_as_float(__builtin_amdgcn_readlane(__float_as_uint(v), l));
}
// quad_perm broadcast of position P within each 4-lane quad (pure VALU DPP)
template<int P>
__device__ __forceinline__ float qb(float v){
  return __int_as_float(__builtin_amdgcn_mov_dpp(__float_as_int(v), P*0x55, 0xF, 0xF, true));
}

// ---------------------------------------------------------------- prep
__global__ void prep_kernel(const float* __restrict__ wf, const float* __restrict__ wb,
                            const float* __restrict__ bf, const float* __restrict__ bb,
                            float* __restrict__ wpad, float* __restrict__ bcomb){
  int idx = blockIdx.x * 256 + threadIdx.x;   // exactly 128*152 threads
  int g = idx / 152, k = idx - g * 152;
  int r = g & 63;
  float sc = ((r >> 4) == 2) ? (-2.f*LOG2E) : (-LOG2E);
  float v = 0.f;
  if (k < 150) v = (g < 64) ? wf[g*150 + k] : wb[(g-64)*150 + k];
  wpad[idx] = v * sc;
  if (idx < 128){
    int rr = idx & 63;
    float sb = ((rr >> 4) == 2) ? (-2.f*LOG2E) : (-LOG2E);
    bcomb[idx] = ((idx < 64) ? bf[idx] : bb[idx - 64]) * sb;
  }
}

// ---------------------------------------------------------------- xg1
// LDS-tiled fp32 GEMM: [131072 x 152] x [152 x 128], block tile 128x128,
// double-buffered K slices of 8, 8x8 register tile per thread.
static constexpr int KS_ = 8, NSLICE = 19;   // 19*8 = 152 (K padded)

__global__ void __launch_bounds__(256) xg1_kernel(
    const float* __restrict__ x, const float* __restrict__ wpad,
    const float* __restrict__ bcomb, float* __restrict__ xg){
  __shared__ float xs[2][KS_][128];
  __shared__ float ws[2][KS_][128];
  const int tid = threadIdx.x;
  const long rowbase = (long)blockIdx.x * 128;

  const int sr = tid >> 1;          // staging row / gate (0..127)
  const int sh = tid & 1;           // staging half (k0+4*sh)
  const float* xrow = x + (rowbase + sr) * 150;
  const float* wrow = wpad + sr * 152;

  auto stage = [&](int ks, int buf){
    const int k0 = ks * KS_;
    // weights: always full float4 (wpad zero-padded to 152)
    float4 wv = *(const float4*)(wrow + k0 + 4*sh);
    // x: last slice second half is k=148..151 -> float2 + zeros
    float4 xv;
    if (k0 + 4*sh + 4 <= 150){
      xv = *(const float4*)(xrow + k0 + 4*sh);
    } else {
      float2 t = *(const float2*)(xrow + 148);
      xv = make_float4(t.x, t.y, 0.f, 0.f);
    }
    #pragma unroll
    for (int j = 0; j < 4; j++){
      xs[buf][4*sh + j][sr] = ((const float*)&xv)[j];
      ws[buf][4*sh + j][sr] = ((const float*)&wv)[j];
    }
  };

  const int tr = tid >> 4;          // row group (0..15): rows 8*tr..
  const int tc = tid & 15;          // gate group (0..15): gates 8*tc..
  float acc[8][8];
  #pragma unroll
  for (int i = 0; i < 8; i++)
    #pragma unroll
    for (int j = 0; j < 8; j++) acc[i][j] = 0.f;

  stage(0, 0);
  __syncthreads();

  for (int ks = 0; ks < NSLICE; ++ks){
    const int cur = ks & 1;
    if (ks < NSLICE - 1) stage(ks + 1, cur ^ 1);
    #pragma unroll
    for (int k = 0; k < KS_; k++){
      float4 xa = *(const float4*)&xs[cur][k][8*tr];
      float4 xb = *(const float4*)&xs[cur][k][8*tr + 4];
      float4 wa = *(const float4*)&ws[cur][k][8*tc];
      float4 wb = *(const float4*)&ws[cur][k][8*tc + 4];
      const float* xf = (const float*)&xa;   // xa,xb contiguous? keep separate
      #pragma unroll
      for (int i = 0; i < 4; i++){
        float xi = ((const float*)&xa)[i];
        acc[i][0] = fmaf(xi, wa.x, acc[i][0]);
        acc[i][1] = fmaf(xi, wa.y, acc[i][1]);
        acc[i][2] = fmaf(xi, wa.z, acc[i][2]);
        acc[i][3] = fmaf(xi, wa.w, acc[i][3]);
        acc[i][4] = fmaf(xi, wb.x, acc[i][4]);
        acc[i][5] = fmaf(xi, wb.y, acc[i][5]);
        acc[i][6] = fmaf(xi, wb.z, acc[i][6]);
        acc[i][7] = fmaf(xi, wb.w, acc[i][7]);
      }
      #pragma unroll
      for (int i = 0; i < 4; i++){
        float xi = ((const float*)&xb)[i];
        acc[4+i][0] = fmaf(xi, wa.x, acc[4+i][0]);
        acc[4+i][1] = fmaf(xi, wa.y, acc[4+i][1]);
        acc[4+i][2] = fmaf(xi, wa.z, acc[4+i][2]);
        acc[4+i][3] = fmaf(xi, wa.w, acc[4+i][3]);
        acc[4+i][4] = fmaf(xi, wb.x, acc[4+i][4]);
        acc[4+i][5] = fmaf(xi, wb.y, acc[4+i][5]);
        acc[4+i][6] = fmaf(xi, wb.z, acc[4+i][6]);
        acc[4+i][7] = fmaf(xi, wb.w, acc[4+i][7]);
      }
      (void)xf;
    }
    __syncthreads();
  }

  float4 bias0 = *(const float4*)(bcomb + 8*tc);
  float4 bias1 = *(const float4*)(bcomb + 8*tc + 4);
  #pragma unroll
  for (int i = 0; i < 8; i++){
    long row = rowbase + 8*tr + i;
    float4 o0 = make_float4(acc[i][0] + bias0.x, acc[i][1] + bias0.y,
                            acc[i][2] + bias0.z, acc[i][3] + bias0.w);
    float4 o1 = make_float4(acc[i][4] + bias1.x, acc[i][5] + bias1.y,
                            acc[i][6] + bias1.z, acc[i][7] + bias1.w);
    float4* dst = (float4*)(xg + row*128 + 8*tc);
    dst[0] = o0; dst[1] = o1;
  }
}

// ---------------------------------------------------------------- lstm1
// One wave per (batch, dir, chunk). lane = 4*unit + gate. DPP gate gather.
// c held scaled: c~ = -2log2e*c. 96-step zero-state warmup, 128-step emit.
template<int DIR>
__device__ __forceinline__ void lstm1_body(
    const float* __restrict__ xg, const float* __restrict__ wh,
    float* __restrict__ h1, int b, int chunk, int lane){
  const int g = lane & 3, u = lane >> 2;
  const int row = g*16 + u;                       // torch gate-major row
  const float ES = (g == 2) ? (-2.f*LOG2E) : (-LOG2E);
  float wrow[16];
  #pragma unroll
  for (int j = 0; j < 16; j++) wrow[j] = wh[row*16 + j] * ES;
  const float A  = (g == 2) ? (-4.f*LOG2E) : 1.f;   // g-gate: k*tanh folded
  const float Bc = (g == 2) ? ( 2.f*LOG2E) : 0.f;

  constexpr int stride = DIR ? -128 : 128;
  constexpr int hstr   = DIR ? -32  : 32;
  const int warm_half = (chunk == 0) ? 0 : WARM_HALF_ITERS;  // 16 steps per iter
  const int it = warm_half + 8;                              // 8 iters emit = 128 steps
  const int warm = warm_half * 16;
  const long tb = DIR ? (2047L - (long)CHUNK*chunk + warm)
                      : ((long)CHUNK*chunk - warm);

  const float* xcol = xg + ((long)b*T_ + tb)*128 + DIR*64 + row;
  float* hptr = h1 + ((long)b*T_ + tb)*32 + DIR*16 + u + (long)g*hstr;

  const bool s0m = (g & 1) != 0;
  const bool s1m = (g & 2) != 0;

  float h = 0.f, c = 0.f;                          // c is scaled state c~
  float xb0[8], xb1[8];
  #pragma unroll
  for (int k = 0; k < 8; k++) xb0[k] = xcol[k*stride];

  auto step = [&](float xgv){
    float a0 = xgv, a1 = 0.f, a2 = 0.f, a3 = 0.f;
    #pragma unroll
    for (int j = 0; j < 4; j++){
      a0 = fmaf(wrow[j],      bcastlane(h, 4*j),        a0);
      a1 = fmaf(wrow[j + 4],  bcastlane(h, 4*(j + 4)),  a1);
      a2 = fmaf(wrow[j + 8],  bcastlane(h, 4*(j + 8)),  a2);
      a3 = fmaf(wrow[j + 12], bcastlane(h, 4*(j + 12)), a3);
    }
    float s = (a0 + a1) + (a2 + a3);
    float act = fmaf(A, fast_rcp(1.f + fast_exp2(s)), Bc);
    float gi = qb<0>(act);
    float gf = qb<1>(act);
    float gG = qb<2>(act);   // = -2log2e * tanh(g_pre)
    float go = qb<3>(act);
    c = fmaf(gf, c, gi * gG);
    h = go * fmaf(2.f, fast_rcp(1.f + fast_exp2(c)), -1.f);
  };
  auto quad = [&](float x0, float x1, float x2, float x3, bool st){
    step(x0); float hA = h;
    step(x1); float hB = h;
    step(x2); float hC = h;
    step(x3); float hD = h;
    float p0 = s0m ? hB : hA;
    float p1 = s0m ? hD : hC;
    if (st) *hptr = s1m ? p1 : p0;   // lane(u,g): h(t0+g*dirsign), unit u
    hptr += 4*hstr;
  };

  for (int i = 0; i < it; ++i){
    const bool st = (i >= warm_half);
    #pragma unroll
    for (int k = 0; k < 8; k++) xb1[k] = xcol[(8 + k)*stride];
    quad(xb0[0], xb0[1], xb0[2], xb0[3], st);
    quad(xb0[4], xb0[5], xb0[6], xb0[7], st);
    xcol += 8*stride;
    if (i < it - 1){
      #pragma unroll
      for (int k = 0; k < 8; k++) xb0[k] = xcol[(8 + k)*stride];
    }
    quad(xb1[0], xb1[1], xb1[2], xb1[3], st);
    quad(xb1[4], xb1[5], xb1[6], xb1[7], st);
    xcol += 8*stride;
  }
}

__global__ void __launch_bounds__(64) lstm1_kernel(
    const float* __restrict__ xg, const float* __restrict__ whf,
    const float* __restrict__ whb, float* __restrict__ h1){
  const int chunk = blockIdx.x & (NCHUNK - 1);
  const int pair  = blockIdx.x >> 4;
  const int b = pair >> 1, dir = pair & 1, lane = threadIdx.x;
  if (dir) lstm1_body<1>(xg, whb, h1, b, chunk, lane);
  else     lstm1_body<0>(xg, whf, h1, b, chunk, lane);
}

// ---------------------------------------------------------------- lstm2
// One wave per (batch, dir, chunk). Phase A: projection of the chunk window
// (in processing order) -> LDS. Phase B: serial H=1 scan with warmup.
template<int DIR>
__device__ __forceinline__ void lstm2_phaseB(
    const float* __restrict__ xg2, const float* __restrict__ uu,
    float* __restrict__ h2, int b, long tb, int warm_half, int nit, int lane){
  const float u0 = uu[0] * (-LOG2E);
  const float u1 = uu[1] * (-LOG2E);
  const float u2 = uu[2] * (-2.f*LOG2E);
  const float u3 = uu[3] * (-LOG2E);
  const float A2 = -4.f*LOG2E, B2 = 2.f*LOG2E;
  constexpr int stsg = DIR ? -1 : 1;
  const float* xp = xg2;                       // processing order, ascending
  float* p = h2 + ((long)b*T_ + tb)*2 + DIR + (long)lane*2*stsg;
  const bool b0 = (lane & 1) != 0, b1 = (lane & 2) != 0, b2 = (lane & 4) != 0;
  const bool lane_st = lane < 8;

  float h = 0.f, c = 0.f;                      // c is scaled state c~
  float4 Aq[8], Bq[8];
  #pragma unroll
  for (int k = 0; k < 8; k++) Aq[k] = *(const float4*)(xp + 4*k);

  auto step = [&](float4 xv)->float{
    float gi = fast_rcp(1.f + fast_exp2(fmaf(u0, h, xv.x)));
    float gf = fast_rcp(1.f + fast_exp2(fmaf(u1, h, xv.y)));
    float gG = fmaf(A2, fast_rcp(1.f + fast_exp2(fmaf(u2, h, xv.z))), B2);
    float go = fast_rcp(1.f + fast_exp2(fmaf(u3, h, xv.w)));
    c = fmaf(gf, c, gi * gG);
    h = go * fmaf(2.f, fast_rcp(1.f + fast_exp2(c)), -1.f);
    return h;
  };
  auto oct = [&](float4* X, bool st){
    float h0v = step(X[0]), h1v = step(X[1]), h2v = step(X[2]), h3v = step(X[3]);
    float h4v = step(X[4]), h5v = step(X[5]), h6v = step(X[6]), h7v = step(X[7]);
    float q0 = b0 ? h1v : h0v;
    float q1 = b0 ? h3v : h2v;
    float q2 = b0 ? h5v : h4v;
    float q3 = b0 ? h7v : h6v;
    float r0 = b1 ? q1 : q0;
    float r1 = b1 ? q3 : q2;
    float sv = b2 ? r1 : r0;
    if (st && lane_st) *p = sv;    // lanes 0-7: coalesced 8-step store
    p += 16*stsg;
  };

  for (int i = 0; i < nit; ++i){
    const bool st = (i >= warm_half);
    #pragma unroll
    for (int k = 0; k < 8; k++) Bq[k] = *(const float4*)(xp + 4*(8 + k));
    oct(Aq, st);
    xp += 32;
    if (i < nit - 1){
      #pragma unroll
      for (int k = 0; k < 8; k++) Aq[k] = *(const float4*)(xp + 4*(8 + k));
    }
    oct(Bq, st);
    xp += 32;
  }
}

__global__ void __launch_bounds__(64) lstm2_kernel(
    const float* __restrict__ h1,
    const float* __restrict__ wi_f, const float* __restrict__ wi_b,
    const float* __restrict__ b_f,  const float* __restrict__ b_b,
    const float* __restrict__ u_f,  const float* __restrict__ u_b,
    float* __restrict__ h2){
  __shared__ float xg2[(WARM_HALF_ITERS*16 + CHUNK) * 4];   // 224*4 floats
  const int chunk = blockIdx.x & (NCHUNK - 1);
  const int pair  = blockIdx.x >> 4;
  const int b = pair >> 1, dir = pair & 1, lane = threadIdx.x;
  const float* wi  = dir ? wi_b : wi_f;
  const float* bbp = dir ? b_b  : b_f;
  const float* uu  = dir ? u_b  : u_f;
  const int warm_half = (chunk == 0) ? 0 : WARM_HALF_ITERS;
  const int nit = warm_half + 8;
  const int warm = warm_half * 16;
  const long tb = dir ? (2047L - (long)CHUNK*chunk + warm)
                      : ((long)CHUNK*chunk - warm);
  const int g = lane & 3, tslot = lane >> 2;
  const float sc = (g == 2) ? (-2.f*LOG2E) : (-LOG2E);
  float4 wv[8];
  #pragma unroll
  for (int q = 0; q < 8; q++){
    float4 w = *(const float4*)(wi + g*32 + q*4);
    wv[q] = make_float4(w.x*sc, w.y*sc, w.z*sc, w.w*sc);
  }
  const float bg = bbp[g] * sc;
  const float* h1b = h1 + (long)b * T_ * 32;
  for (int i = 0; i < nit; i++){
    int s = tslot + 16*i;                 // local step in processing order
    long t = dir ? (tb - s) : (tb + s);
    const float4* hr = (const float4*)(h1b + t * 32);
    float a = bg;
    #pragma unroll
    for (int q = 0; q < 8; q++){
      float4 hv = hr[q];
      a = fmaf(hv.x, wv[q].x, a); a = fmaf(hv.y, wv[q].y, a);
      a = fmaf(hv.z, wv[q].z, a); a = fmaf(hv.w, wv[q].w, a);
    }
    xg2[s*4 + g] = a;
  }
  __syncthreads();
  if (dir) lstm2_phaseB<1>(xg2, uu, h2, b, tb, warm_half, nit, lane);
  else     lstm2_phaseB<0>(xg2, uu, h2, b, tb, warm_half, nit, lane);
}

// ---------------------------------------------------------------- head
__global__ void __launch_bounds__(64) head_kernel(
    const float* __restrict__ h2, const float* __restrict__ fcw,
    const float* __restrict__ fcb, float* __restrict__ out){
  const int blk = blockIdx.x;
  const int b = blk / 3, cls = blk - b*3;
  const int lane = threadIdx.x;
  const float w0 = fcw[cls*2], w1 = fcw[cls*2 + 1], bb = fcb[cls];
  const float* hp = h2 + (long)b * T_ * 2;
  float l[32];
  float m = -1e30f;
  #pragma unroll
  for (int i = 0; i < 32; i++){
    int t = lane + 64*i;
    float2 hv = *(const float2*)(hp + t*2);
    l[i] = fmaf(hv.x, w0, fmaf(hv.y, w1, bb));
    m = fmaxf(m, l[i]);
  }
  #pragma unroll
  for (int s = 1; s < 64; s <<= 1) m = fmaxf(m, __shfl_xor(m, s));
  float sum = 0.f;
  #pragma unroll
  for (int i = 0; i < 32; i++){
    l[i] = fast_exp2((l[i] - m) * LOG2E);
    sum += l[i];
  }
  #pragma unroll
  for (int s = 1; s < 64; s <<= 1) sum += __shfl_xor(sum, s);
  float inv = 1.f / sum;
  float* ob = out + (long)b * T_ * 3 + cls;
  #pragma unroll
  for (int i = 0; i < 32; i++){
    int t = lane + 64*i;
    ob[(long)t * 3] = l[i] * inv;
  }
}

// ---------------------------------------------------------------- launch
extern "C" void kernel_launch(void* const* d_in, const int* in_sizes, int n_in,
                              void* d_out, int out_size, void* d_ws, size_t ws_size,
                              hipStream_t stream) {
  const float* x       = (const float*)d_in[0];
  const float* w_ih1_f = (const float*)d_in[1];
  const float* w_hh1_f = (const float*)d_in[2];
  const float* b1_f    = (const float*)d_in[3];
  const float* w_ih1_b = (const float*)d_in[4];
  const float* w_hh1_b = (const float*)d_in[5];
  const float* b1_b    = (const float*)d_in[6];
  const float* w_ih2_f = (const float*)d_in[7];
  const float* w_hh2_f = (const float*)d_in[8];
  const float* b2_f    = (const float*)d_in[9];
  const float* w_ih2_b = (const float*)d_in[10];
  const float* w_hh2_b = (const float*)d_in[11];
  const float* b2_b    = (const float*)d_in[12];
  const float* fc_w    = (const float*)d_in[13];
  const float* fc_b    = (const float*)d_in[14];
  float* out = (float*)d_out;
  float* ws  = (float*)d_ws;

  float* xg1   = ws + XG1_OFF;
  float* h1    = ws + H1_OFF;
  float* h2    = ws + H2_OFF;
  float* wpad  = ws + WPAD_OFF;
  float* bcomb = ws + BCOMB_OFF;

  prep_kernel<<<(128*152)/256, 256, 0, stream>>>(w_ih1_f, w_ih1_b, b1_f, b1_b, wpad, bcomb);
  xg1_kernel<<<(B_*T_)/128, 256, 0, stream>>>(x, wpad, bcomb, xg1);
  lstm1_kernel<<<B_*2*NCHUNK, 64, 0, stream>>>(xg1, w_hh1_f, w_hh1_b, h1);
  lstm2_kernel<<<B_*2*NCHUNK, 64, 0, stream>>>(h1, w_ih2_f, w_ih2_b, b2_f, b2_b,
                                               w_hh2_f, w_hh2_b, h2);
  head_kernel<<<B_*C_, 64, 0, stream>>>(h2, fc_w, fc_b, out);
}

// Round 7
// 169.966 us; speedup vs baseline: 5.6135x; 1.1369x over previous
//
#include <hip/hip_runtime.h>
#include <hip/hip_bf16.h>

static constexpr int B_ = 64, T_ = 2048, I_ = 150, C_ = 3;

// chunked-scan parameters: 16 chunks x 128 steps, 96-step warm-start
static constexpr int NCHUNK = 16, CHUNK = 128, WARM_HALF_ITERS = 6; // 6*16=96 steps

// workspace layout (float offsets)
static constexpr long XG1_OFF   = 0;                       // B*T*128 bf16 -> 8388608 floats used
static constexpr long H1_OFF    = 16777216;                // B*T*32  = 4194304
static constexpr long H2_OFF    = H1_OFF + 4194304;        // B*T*2   = 262144
static constexpr long WBF_OFF   = H2_OFF + 262144;         // 128*160 bf16 = 10240 floats
static constexpr long BCOMB_OFF = WBF_OFF + 10240;         // 128

#define LOG2E 1.4426950408889634f

__device__ __forceinline__ float fast_exp2(float x){ return __builtin_amdgcn_exp2f(x); }
__device__ __forceinline__ float fast_rcp(float x){ return __builtin_amdgcn_rcpf(x); }
__device__ __forceinline__ float bcastlane(float v, int l){
  return __uint_as_float(__builtin_amdgcn_readlane(__float_as_uint(v), l));
}
template<int P>
__device__ __forceinline__ float qb(float v){
  return __int_as_float(__builtin_amdgcn_mov_dpp(__float_as_int(v), P*0x55, 0xF, 0xF, true));
}
__device__ __forceinline__ unsigned short f2bf(float f){
  __hip_bfloat16 h = __float2bfloat16(f);          // RTNE
  return *reinterpret_cast<unsigned short*>(&h);
}
__device__ __forceinline__ float bf2f(unsigned short u){
  return __uint_as_float(((unsigned)u) << 16);
}
__device__ __forceinline__ unsigned pack2bf(float a, float b){
  unsigned r;
  asm volatile("v_cvt_pk_bf16_f32 %0, %1, %2" : "=v"(r) : "v"(a), "v"(b));
  return r;
}

using bf16x8 = __attribute__((ext_vector_type(8))) short;
using f32x4  = __attribute__((ext_vector_type(4))) float;

// ---------------------------------------------------------------- prep
// wbf[128][160] bf16: prescaled (-log2e / -2log2e for g rows), zero-padded.
// bcomb[128] fp32 prescaled bias.
__global__ void prep_kernel(const float* __restrict__ wf, const float* __restrict__ wb,
                            const float* __restrict__ bf, const float* __restrict__ bb,
                            unsigned short* __restrict__ wbf, float* __restrict__ bcomb){
  int idx = blockIdx.x * 256 + threadIdx.x;   // exactly 128*160 threads
  int g = idx / 160, k = idx - g * 160;
  int r = g & 63;
  float sc = ((r >> 4) == 2) ? (-2.f*LOG2E) : (-LOG2E);
  float v = 0.f;
  if (k < 150) v = (g < 64) ? wf[g*150 + k] : wb[(g-64)*150 + k];
  wbf[idx] = f2bf(v * sc);
  if (idx < 128){
    int rr = idx & 63;
    float sb = ((rr >> 4) == 2) ? (-2.f*LOG2E) : (-LOG2E);
    bcomb[idx] = ((idx < 64) ? bf[idx] : bb[idx - 64]) * sb;
  }
}

// ---------------------------------------------------------------- xg1 (MFMA)
// [131072 x 152] x [152 x 128] in bf16 via mfma_f32_16x16x32_bf16.
// Block: 128 rows x 128 gates, 4 waves (2x2), K padded to 160 (5 steps of 32).
// LDS holds fragments in lane-linear order -> conflict-free b128 reads.
__global__ void __launch_bounds__(256) xg1_kernel(
    const float* __restrict__ x, const unsigned short* __restrict__ wbf,
    const float* __restrict__ bcomb, unsigned short* __restrict__ xg){
  __shared__ uint4 wlds[8][5][64];     // [gateTile][kstep][lane] 40960B
  __shared__ uint4 xlds[2][8][64];     // [buf][rowTile][lane]    16384B
  const int tid = threadIdx.x;
  const long rowbase = (long)blockIdx.x * 128;

  // ---- stage W fragments (once per block) ----
  for (int idx = tid; idx < 8*5*64; idx += 256){
    int gt  = idx / 320;
    int rem = idx - gt*320;
    int ks  = rem >> 6;
    int l   = rem & 63;
    const unsigned short* src = wbf + (gt*16 + (l & 15))*160 + ks*32 + (l >> 4)*8;
    wlds[gt][ks][l] = *(const uint4*)src;
  }

  // ---- X staging: thread (row, part) covers 16 k of one row ----
  const int srow  = tid >> 1;          // 0..127
  const int part  = tid & 1;
  const float* xrow = x + (rowbase + srow) * 150;
  const int xtile = srow >> 4;
  const int rl    = srow & 15;

  auto stageX = [&](int ks, int buf, bool tail){
    const int k0 = ks*32 + part*16;
    #pragma unroll
    for (int q = 0; q < 4; q++){
      const int kk = k0 + q*4;
      uint2 pk;
      if (!tail || q == 0){                       // fully in-bounds
        float2 u = *(const float2*)(xrow + kk);
        float2 v = *(const float2*)(xrow + kk + 2);
        pk.x = pack2bf(u.x, u.y);
        pk.y = pack2bf(v.x, v.y);
      } else if (q == 1){                         // k = 148..151
        float2 u = *(const float2*)(xrow + 148);
        pk.x = pack2bf(u.x, u.y);
        pk.y = 0u;
      } else {                                    // k >= 152
        pk.x = 0u; pk.y = 0u;
      }
      const int lane = (part*2 + (q >> 1))*16 + rl;
      ((uint2*)&xlds[buf][xtile][lane])[q & 1] = pk;
    }
  };

  const int w  = tid >> 6;       // wave id
  const int l  = tid & 63;
  const int wr = w >> 1;         // row half   (0..1)
  const int wc = w & 1;          // gate half  (0..1)

  f32x4 acc[4][4];
  #pragma unroll
  for (int i = 0; i < 4; i++)
    #pragma unroll
    for (int j = 0; j < 4; j++) acc[i][j] = (f32x4){0.f, 0.f, 0.f, 0.f};

  stageX(0, 0, false);
  __syncthreads();

  for (int ks = 0; ks < 5; ++ks){
    const int cur = ks & 1;
    if (ks < 4) stageX(ks + 1, cur ^ 1, (ks + 1 == 4) && (part == 1));
    bf16x8 afr[4], bfr[4];
    #pragma unroll
    for (int tm = 0; tm < 4; tm++)
      afr[tm] = *(const bf16x8*)&xlds[cur][wr*4 + tm][l];
    #pragma unroll
    for (int tn = 0; tn < 4; tn++)
      bfr[tn] = *(const bf16x8*)&wlds[wc*4 + tn][ks][l];
    #pragma unroll
    for (int tm = 0; tm < 4; tm++)
      #pragma unroll
      for (int tn = 0; tn < 4; tn++)
        acc[tm][tn] = __builtin_amdgcn_mfma_f32_16x16x32_bf16(
            afr[tm], bfr[tn], acc[tm][tn], 0, 0, 0);
    __syncthreads();
  }

  // ---- epilogue: bias + bf16 store. C map: col=l&15, row=(l>>4)*4+reg ----
  const int crow = (l >> 4) * 4;
  const int ccol = l & 15;
  #pragma unroll
  for (int tn = 0; tn < 4; tn++){
    const int gate = wc*64 + tn*16 + ccol;
    const float bias = bcomb[gate];
    #pragma unroll
    for (int tm = 0; tm < 4; tm++){
      const long r0 = rowbase + wr*64 + tm*16 + crow;
      #pragma unroll
      for (int r = 0; r < 4; r++)
        xg[(r0 + r)*128 + gate] = f2bf(acc[tm][tn][r] + bias);
    }
  }
}

// ---------------------------------------------------------------- lstm1
// One wave per (batch, dir, chunk). lane = 4*unit + gate. DPP gate gather.
// c held scaled: c~ = -2log2e*c. xg read as bf16 (cvt on prefetch path).
template<int DIR>
__device__ __forceinline__ void lstm1_body(
    const unsigned short* __restrict__ xg, const float* __restrict__ wh,
    float* __restrict__ h1, int b, int chunk, int lane){
  const int g = lane & 3, u = lane >> 2;
  const int row = g*16 + u;                       // torch gate-major row
  const float ES = (g == 2) ? (-2.f*LOG2E) : (-LOG2E);
  float wrow[16];
  #pragma unroll
  for (int j = 0; j < 16; j++) wrow[j] = wh[row*16 + j] * ES;
  const float A  = (g == 2) ? (-4.f*LOG2E) : 1.f;   // g-gate: k*tanh folded
  const float Bc = (g == 2) ? ( 2.f*LOG2E) : 0.f;

  constexpr int stride = DIR ? -128 : 128;
  constexpr int hstr   = DIR ? -32  : 32;
  const int warm_half = (chunk == 0) ? 0 : WARM_HALF_ITERS;  // 16 steps per iter
  const int it = warm_half + 8;                              // 8 iters emit = 128 steps
  const int warm = warm_half * 16;
  const long tb = DIR ? (2047L - (long)CHUNK*chunk + warm)
                      : ((long)CHUNK*chunk - warm);

  const unsigned short* xcol = xg + ((long)b*T_ + tb)*128 + DIR*64 + row;
  float* hptr = h1 + ((long)b*T_ + tb)*32 + DIR*16 + u + (long)g*hstr;

  const bool s0m = (g & 1) != 0;
  const bool s1m = (g & 2) != 0;

  float h = 0.f, c = 0.f;                          // c is scaled state c~
  float xb0[8], xb1[8];
  #pragma unroll
  for (int k = 0; k < 8; k++) xb0[k] = bf2f(xcol[k*stride]);

  auto step = [&](float xgv){
    float a0 = xgv, a1 = 0.f, a2 = 0.f, a3 = 0.f;
    #pragma unroll
    for (int j = 0; j < 4; j++){
      a0 = fmaf(wrow[j],      bcastlane(h, 4*j),        a0);
      a1 = fmaf(wrow[j + 4],  bcastlane(h, 4*(j + 4)),  a1);
      a2 = fmaf(wrow[j + 8],  bcastlane(h, 4*(j + 8)),  a2);
      a3 = fmaf(wrow[j + 12], bcastlane(h, 4*(j + 12)), a3);
    }
    float s = (a0 + a1) + (a2 + a3);
    float act = fmaf(A, fast_rcp(1.f + fast_exp2(s)), Bc);
    float gi = qb<0>(act);
    float gf = qb<1>(act);
    float gG = qb<2>(act);   // = -2log2e * tanh(g_pre)
    float go = qb<3>(act);
    c = fmaf(gf, c, gi * gG);
    h = go * fmaf(2.f, fast_rcp(1.f + fast_exp2(c)), -1.f);
  };
  auto quad = [&](float x0, float x1, float x2, float x3, bool st){
    step(x0); float hA = h;
    step(x1); float hB = h;
    step(x2); float hC = h;
    step(x3); float hD = h;
    float p0 = s0m ? hB : hA;
    float p1 = s0m ? hD : hC;
    if (st) *hptr = s1m ? p1 : p0;   // lane(u,g): h(t0+g*dirsign), unit u
    hptr += 4*hstr;
  };

  for (int i = 0; i < it; ++i){
    const bool st = (i >= warm_half);
    #pragma unroll
    for (int k = 0; k < 8; k++) xb1[k] = bf2f(xcol[(8 + k)*stride]);
    quad(xb0[0], xb0[1], xb0[2], xb0[3], st);
    quad(xb0[4], xb0[5], xb0[6], xb0[7], st);
    xcol += 8*stride;
    if (i < it - 1){
      #pragma unroll
      for (int k = 0; k < 8; k++) xb0[k] = bf2f(xcol[(8 + k)*stride]);
    }
    quad(xb1[0], xb1[1], xb1[2], xb1[3], st);
    quad(xb1[4], xb1[5], xb1[6], xb1[7], st);
    xcol += 8*stride;
  }
}

__global__ void __launch_bounds__(64) lstm1_kernel(
    const unsigned short* __restrict__ xg, const float* __restrict__ whf,
    const float* __restrict__ whb, float* __restrict__ h1){
  const int chunk = blockIdx.x & (NCHUNK - 1);
  const int pair  = blockIdx.x >> 4;
  const int b = pair >> 1, dir = pair & 1, lane = threadIdx.x;
  if (dir) lstm1_body<1>(xg, whb, h1, b, chunk, lane);
  else     lstm1_body<0>(xg, whf, h1, b, chunk, lane);
}

// ---------------------------------------------------------------- lstm2
// One wave per (batch, dir, chunk). Phase A: projection of the chunk window
// (in processing order) -> LDS. Phase B: serial H=1 scan with warmup.
template<int DIR>
__device__ __forceinline__ void lstm2_phaseB(
    const float* __restrict__ xg2, const float* __restrict__ uu,
    float* __restrict__ h2, int b, long tb, int warm_half, int nit, int lane){
  const float u0 = uu[0] * (-LOG2E);
  const float u1 = uu[1] * (-LOG2E);
  const float u2 = uu[2] * (-2.f*LOG2E);
  const float u3 = uu[3] * (-LOG2E);
  const float A2 = -4.f*LOG2E, B2 = 2.f*LOG2E;
  constexpr int stsg = DIR ? -1 : 1;
  const float* xp = xg2;                       // processing order, ascending
  float* p = h2 + ((long)b*T_ + tb)*2 + DIR + (long)lane*2*stsg;
  const bool b0 = (lane & 1) != 0, b1 = (lane & 2) != 0, b2 = (lane & 4) != 0;
  const bool lane_st = lane < 8;

  float h = 0.f, c = 0.f;                      // c is scaled state c~
  float4 Aq[8], Bq[8];
  #pragma unroll
  for (int k = 0; k < 8; k++) Aq[k] = *(const float4*)(xp + 4*k);

  auto step = [&](float4 xv)->float{
    float gi = fast_rcp(1.f + fast_exp2(fmaf(u0, h, xv.x)));
    float gf = fast_rcp(1.f + fast_exp2(fmaf(u1, h, xv.y)));
    float gG = fmaf(A2, fast_rcp(1.f + fast_exp2(fmaf(u2, h, xv.z))), B2);
    float go = fast_rcp(1.f + fast_exp2(fmaf(u3, h, xv.w)));
    c = fmaf(gf, c, gi * gG);
    h = go * fmaf(2.f, fast_rcp(1.f + fast_exp2(c)), -1.f);
    return h;
  };
  auto oct = [&](float4* X, bool st){
    float h0v = step(X[0]), h1v = step(X[1]), h2v = step(X[2]), h3v = step(X[3]);
    float h4v = step(X[4]), h5v = step(X[5]), h6v = step(X[6]), h7v = step(X[7]);
    float q0 = b0 ? h1v : h0v;
    float q1 = b0 ? h3v : h2v;
    float q2 = b0 ? h5v : h4v;
    float q3 = b0 ? h7v : h6v;
    float r0 = b1 ? q1 : q0;
    float r1 = b1 ? q3 : q2;
    float sv = b2 ? r1 : r0;
    if (st && lane_st) *p = sv;    // lanes 0-7: coalesced 8-step store
    p += 16*stsg;
  };

  for (int i = 0; i < nit; ++i){
    const bool st = (i >= warm_half);
    #pragma unroll
    for (int k = 0; k < 8; k++) Bq[k] = *(const float4*)(xp + 4*(8 + k));
    oct(Aq, st);
    xp += 32;
    if (i < nit - 1){
      #pragma unroll
      for (int k = 0; k < 8; k++) Aq[k] = *(const float4*)(xp + 4*(8 + k));
    }
    oct(Bq, st);
    xp += 32;
  }
}

__global__ void __launch_bounds__(64) lstm2_kernel(
    const float* __restrict__ h1,
    const float* __restrict__ wi_f, const float* __restrict__ wi_b,
    const float* __restrict__ b_f,  const float* __restrict__ b_b,
    const float* __restrict__ u_f,  const float* __restrict__ u_b,
    float* __restrict__ h2){
  __shared__ float xg2[(WARM_HALF_ITERS*16 + CHUNK) * 4];   // 224*4 floats
  const int chunk = blockIdx.x & (NCHUNK - 1);
  const int pair  = blockIdx.x >> 4;
  const int b = pair >> 1, dir = pair & 1, lane = threadIdx.x;
  const float* wi  = dir ? wi_b : wi_f;
  const float* bbp = dir ? b_b  : b_f;
  const float* uu  = dir ? u_b  : u_f;
  const int warm_half = (chunk == 0) ? 0 : WARM_HALF_ITERS;
  const int nit = warm_half + 8;
  const int warm = warm_half * 16;
  const long tb = dir ? (2047L - (long)CHUNK*chunk + warm)
                      : ((long)CHUNK*chunk - warm);
  const int g = lane & 3, tslot = lane >> 2;
  const float sc = (g == 2) ? (-2.f*LOG2E) : (-LOG2E);
  float4 wv[8];
  #pragma unroll
  for (int q = 0; q < 8; q++){
    float4 w = *(const float4*)(wi + g*32 + q*4);
    wv[q] = make_float4(w.x*sc, w.y*sc, w.z*sc, w.w*sc);
  }
  const float bg = bbp[g] * sc;
  const float* h1b = h1 + (long)b * T_ * 32;
  for (int i = 0; i < nit; i++){
    int s = tslot + 16*i;                 // local step in processing order
    long t = dir ? (tb - s) : (tb + s);
    const float4* hr = (const float4*)(h1b + t * 32);
    float a = bg;
    #pragma unroll
    for (int q = 0; q < 8; q++){
      float4 hv = hr[q];
      a = fmaf(hv.x, wv[q].x, a); a = fmaf(hv.y, wv[q].y, a);
      a = fmaf(hv.z, wv[q].z, a); a = fmaf(hv.w, wv[q].w, a);
    }
    xg2[s*4 + g] = a;
  }
  __syncthreads();
  if (dir) lstm2_phaseB<1>(xg2, uu, h2, b, tb, warm_half, nit, lane);
  else     lstm2_phaseB<0>(xg2, uu, h2, b, tb, warm_half, nit, lane);
}

// ---------------------------------------------------------------- head
__global__ void __launch_bounds__(64) head_kernel(
    const float* __restrict__ h2, const float* __restrict__ fcw,
    const float* __restrict__ fcb, float* __restrict__ out){
  const int blk = blockIdx.x;
  const int b = blk / 3, cls = blk - b*3;
  const int lane = threadIdx.x;
  const float w0 = fcw[cls*2], w1 = fcw[cls*2 + 1], bb = fcb[cls];
  const float* hp = h2 + (long)b * T_ * 2;
  float l[32];
  float m = -1e30f;
  #pragma unroll
  for (int i = 0; i < 32; i++){
    int t = lane + 64*i;
    float2 hv = *(const float2*)(hp + t*2);
    l[i] = fmaf(hv.x, w0, fmaf(hv.y, w1, bb));
    m = fmaxf(m, l[i]);
  }
  #pragma unroll
  for (int s = 1; s < 64; s <<= 1) m = fmaxf(m, __shfl_xor(m, s));
  float sum = 0.f;
  #pragma unroll
  for (int i = 0; i < 32; i++){
    l[i] = fast_exp2((l[i] - m) * LOG2E);
    sum += l[i];
  }
  #pragma unroll
  for (int s = 1; s < 64; s <<= 1) sum += __shfl_xor(sum, s);
  float inv = 1.f / sum;
  float* ob = out + (long)b * T_ * 3 + cls;
  #pragma unroll
  for (int i = 0; i < 32; i++){
    int t = lane + 64*i;
    ob[(long)t * 3] = l[i] * inv;
  }
}

// ---------------------------------------------------------------- launch
extern "C" void kernel_launch(void* const* d_in, const int* in_sizes, int n_in,
                              void* d_out, int out_size, void* d_ws, size_t ws_size,
                              hipStream_t stream) {
  const float* x       = (const float*)d_in[0];
  const float* w_ih1_f = (const float*)d_in[1];
  const float* w_hh1_f = (const float*)d_in[2];
  const float* b1_f    = (const float*)d_in[3];
  const float* w_ih1_b = (const float*)d_in[4];
  const float* w_hh1_b = (const float*)d_in[5];
  const float* b1_b    = (const float*)d_in[6];
  const float* w_ih2_f = (const float*)d_in[7];
  const float* w_hh2_f = (const float*)d_in[8];
  const float* b2_f    = (const float*)d_in[9];
  const float* w_ih2_b = (const float*)d_in[10];
  const float* w_hh2_b = (const float*)d_in[11];
  const float* b2_b    = (const float*)d_in[12];
  const float* fc_w    = (const float*)d_in[13];
  const float* fc_b    = (const float*)d_in[14];
  float* out = (float*)d_out;
  float* ws  = (float*)d_ws;

  unsigned short* xg1 = (unsigned short*)(ws + XG1_OFF);
  float* h1    = ws + H1_OFF;
  float* h2    = ws + H2_OFF;
  unsigned short* wbf = (unsigned short*)(ws + WBF_OFF);
  float* bcomb = ws + BCOMB_OFF;

  prep_kernel<<<(128*160)/256, 256, 0, stream>>>(w_ih1_f, w_ih1_b, b1_f, b1_b, wbf, bcomb);
  xg1_kernel<<<(B_*T_)/128, 256, 0, stream>>>(x, wbf, bcomb, xg1);
  lstm1_kernel<<<B_*2*NCHUNK, 64, 0, stream>>>(xg1, w_hh1_f, w_hh1_b, h1);
  lstm2_kernel<<<B_*2*NCHUNK, 64, 0, stream>>>(h1, w_ih2_f, w_ih2_b, b2_f, b2_b,
                                               w_hh2_f, w_hh2_b, h2);
  head_kernel<<<B_*C_, 64, 0, stream>>>(h2, fc_w, fc_b, out);
}